// Round 18
// baseline (429.218 us; speedup 1.0000x reference)
//
#include <hip/hip_runtime.h>
#include <math.h>

#define NN 4096
#define HH 256
#define BATCH 8
#define TOPK 32
#define NSEL 64
#define LN_EPS 1e-5f

typedef float f32x4 __attribute__((ext_vector_type(4)));
typedef short bf16x8 __attribute__((ext_vector_type(8)));

__device__ __forceinline__ unsigned short f2bf(float x) {
  unsigned u = __float_as_uint(x);
  u += 0x7FFF + ((u >> 16) & 1);  // RNE
  return (unsigned short)(u >> 16);
}
__device__ __forceinline__ float bf2f(unsigned short h) {
  return __uint_as_float(((unsigned)h) << 16);
}

// async global->LDS, 16B per lane; LDS dest is wave-uniform base + lane*16
__device__ __forceinline__ void gload16(const void* g, void* l) {
  __builtin_amdgcn_global_load_lds(
      (const __attribute__((address_space(1))) void*)g,
      (__attribute__((address_space(3))) void*)l, 16, 0, 0);
}

// one BK=32 K-step: 4x4 fragment MFMAs from [g:4][row:128][8] LDS tiles
__device__ __forceinline__ void mfma_tile(const unsigned short* Al,
                                          const unsigned short* Bl,
                                          int wr, int wc, int lane,
                                          f32x4 acc[4][4]) {
  const int g = lane >> 4, r = lane & 15;
  bf16x8 a[4], b[4];
#pragma unroll
  for (int i = 0; i < 4; ++i)
    a[i] = *reinterpret_cast<const bf16x8*>(Al + ((size_t)(g * 128 + wr * 64 + i * 16 + r)) * 8);
#pragma unroll
  for (int j = 0; j < 4; ++j)
    b[j] = *reinterpret_cast<const bf16x8*>(Bl + ((size_t)(g * 128 + wc * 64 + j * 16 + r)) * 8);
#pragma unroll
  for (int i = 0; i < 4; ++i)
#pragma unroll
    for (int j = 0; j < 4; ++j)
      acc[i][j] = __builtin_amdgcn_mfma_f32_16x16x32_bf16(a[i], b[j], acc[i][j], 0, 0, 0);
}

// ---------------------------------------------------------------------------
// K0: bf16 (hi-only) pack of n1/n2 into GEMM LDS slot order. 8 K-steps.
// ---------------------------------------------------------------------------
__global__ __launch_bounds__(256) void k_pack(
    const float* __restrict__ n1, const float* __restrict__ n2,
    unsigned short* __restrict__ apack, unsigned short* __restrict__ bpack) {
  const int u = blockIdx.x * 256 + threadIdx.x;  // 0..131071
  const float* srcm = blockIdx.y ? n2 : n1;
  unsigned short* dstm = blockIdx.y ? bpack : apack;
  const int row = u >> 5, kg = u & 31;
  const int st = kg >> 2, g = kg & 3;
  const int bm = row >> 7, slot = g * 128 + (row & 127);

  const float4 v0 = *reinterpret_cast<const float4*>(srcm + (size_t)row * HH + kg * 8);
  const float4 v1 = *reinterpret_cast<const float4*>(srcm + (size_t)row * HH + kg * 8 + 4);
  const float xs[8] = {v0.x, v0.y, v0.z, v0.w, v1.x, v1.y, v1.z, v1.w};
  union { unsigned short s[8]; uint4 q; } hi;
#pragma unroll
  for (int e = 0; e < 8; ++e) hi.s[e] = f2bf(xs[e]);
  *reinterpret_cast<uint4*>(dstm + ((size_t)(bm * 8 + st) * 512 + slot) * 8) = hi.q;
}

// ---------------------------------------------------------------------------
// K0b: src fp32 -> bf16 (same [b][n][h] layout). Runs AFTER k_topk64.
// ---------------------------------------------------------------------------
__global__ __launch_bounds__(256) void k_srcpack(
    const float* __restrict__ src, unsigned short* __restrict__ s16) {
  const size_t i = ((size_t)blockIdx.x * 256 + threadIdx.x) * 8;
  const float4 v0 = *reinterpret_cast<const float4*>(src + i);
  const float4 v1 = *reinterpret_cast<const float4*>(src + i + 4);
  const float xs[8] = {v0.x, v0.y, v0.z, v0.w, v1.x, v1.y, v1.z, v1.w};
  union { unsigned short s[8]; uint4 q; } p;
#pragma unroll
  for (int e = 0; e < 8; ++e) p.s[e] = f2bf(xs[e]);
  *reinterpret_cast<uint4*>(s16 + i) = p.q;
}

// ---------------------------------------------------------------------------
// K0c: w1/w2 [256][256] fp32 -> bf16 GEMM slot-order packs.
// ---------------------------------------------------------------------------
__global__ __launch_bounds__(256) void k_packw(
    const float* __restrict__ w1, const float* __restrict__ w2,
    unsigned short* __restrict__ w1pack, unsigned short* __restrict__ w2pack) {
  const int u = blockIdx.x * 256 + threadIdx.x;  // 0..8191
  const float* srcm = blockIdx.y ? w2 : w1;
  unsigned short* dstm = blockIdx.y ? w2pack : w1pack;
  const int row = u >> 5, kg = u & 31;
  const int st = kg >> 2, g = kg & 3;
  const int bn = row >> 7, slot = g * 128 + (row & 127);

  const float4 v0 = *reinterpret_cast<const float4*>(srcm + (size_t)row * HH + kg * 8);
  const float4 v1 = *reinterpret_cast<const float4*>(srcm + (size_t)row * HH + kg * 8 + 4);
  const float xs[8] = {v0.x, v0.y, v0.z, v0.w, v1.x, v1.y, v1.z, v1.w};
  union { unsigned short s[8]; uint4 q; } p;
#pragma unroll
  for (int e = 0; e < 8; ++e) p.s[e] = f2bf(xs[e]);
  *reinterpret_cast<uint4*>(dstm + ((size_t)(bn * 8 + st) * 512 + slot) * 8) = p.q;
}

// ---------------------------------------------------------------------------
// K1a: adjb ~= bf16(n1 @ n2^T), ONE bf16 phase. Selection-only values:
// storage rounding (+-0.125) + GEMM bf16 error both << v32-v64 gap (~0.93);
// exact values recomputed by k_refine. 8 K-steps, XCD-swizzled. grid 1024.
// ---------------------------------------------------------------------------
__global__ __launch_bounds__(256) void k_adjgemm_pk(
    const unsigned short* __restrict__ apack,
    const unsigned short* __restrict__ bpack,
    unsigned short* __restrict__ adjb) {
  __shared__ __align__(16) unsigned short Al[512 * 8];
  __shared__ __align__(16) unsigned short Bl[512 * 8];
  const int tid = threadIdx.x;
  const int lane = tid & 63, wid = tid >> 6;
  const int wr = wid >> 1, wc = wid & 1;
  const int wgid = (blockIdx.x & 7) * 128 + (blockIdx.x >> 3);  // XCD swizzle
  const int bm = wgid >> 5, bn = wgid & 31;
  const int m0 = bm * 128, n0 = bn * 128;

  f32x4 acc[4][4];
#pragma unroll
  for (int i = 0; i < 4; ++i)
#pragma unroll
    for (int j = 0; j < 4; ++j) acc[i][j] = (f32x4){0.f, 0.f, 0.f, 0.f};

  unsigned short* lA0 = Al + (size_t)(wid * 64) * 8;
  unsigned short* lA1 = Al + (size_t)(256 + wid * 64) * 8;
  unsigned short* lB0 = Bl + (size_t)(wid * 64) * 8;
  unsigned short* lB1 = Bl + (size_t)(256 + wid * 64) * 8;

  for (int t = 0; t < 8; ++t) {
    const unsigned short* ga = apack + (size_t)(bm * 8 + t) * 4096;
    const unsigned short* gb = bpack + (size_t)(bn * 8 + t) * 4096;
    __syncthreads();
    gload16(ga + (size_t)tid * 8, lA0);
    gload16(ga + (size_t)(256 + tid) * 8, lA1);
    gload16(gb + (size_t)tid * 8, lB0);
    gload16(gb + (size_t)(256 + tid) * 8, lB1);
    __syncthreads();
    mfma_tile(Al, Bl, wr, wc, lane, acc);
  }

  const int crow = m0 + wr * 64 + (lane >> 4) * 4;
  const int ccol = n0 + wc * 64 + (lane & 15);
#pragma unroll
  for (int i = 0; i < 4; ++i)
#pragma unroll
    for (int j = 0; j < 4; ++j) {
      unsigned short* cp = adjb + (size_t)(crow + i * 16) * NN + ccol + j * 16;
#pragma unroll
      for (int q = 0; q < 4; ++q) cp[(size_t)q * NN] = f2bf(acc[i][j][q]);
    }
}

// ---------------------------------------------------------------------------
// K1b: per-row approx top-64 candidate indices via ballot-bisection, from
// the bf16 adj (half the scan traffic). Keys unique via idx field.
// ---------------------------------------------------------------------------
__global__ __launch_bounds__(256) void k_topk64(
    const unsigned short* __restrict__ adjb, int* __restrict__ cand) {
  const int tid = threadIdx.x;
  const int wid = tid >> 6, lane = tid & 63;
  const int r = blockIdx.x * 4 + wid;
  const bf16x8* rp8 = reinterpret_cast<const bf16x8*>(adjb + (size_t)r * NN);

#define KEY(v, ix) ((((unsigned long long)__float_as_uint(v)) << 32) | \
                    (unsigned)(NN - 1 - (ix)))

  unsigned long long k1 = 0, k2 = 0, k3 = 0, k4 = 0;
  unsigned long long k5 = 0, k6 = 0, k7 = 0, k8 = 0;

#define INS4(kk)                                              \
  do { const unsigned long long _k = (kk);                    \
    if (_k > k4) {                                            \
      if (_k > k1)      { k4 = k3; k3 = k2; k2 = k1; k1 = _k; } \
      else if (_k > k2) { k4 = k3; k3 = k2; k2 = _k; }        \
      else if (_k > k3) { k4 = k3; k3 = _k; }                 \
      else              { k4 = _k; } } } while (0)
#define INS8(kk)                                              \
  do { const unsigned long long _k = (kk);                    \
    if (_k > k8) {                                            \
      if (_k > k5)      { k8 = k7; k7 = k6; k6 = k5; k5 = _k; } \
      else if (_k > k6) { k8 = k7; k7 = k6; k6 = _k; }        \
      else if (_k > k7) { k8 = k7; k7 = _k; }                 \
      else              { k8 = _k; } } } while (0)

#pragma unroll
  for (int j = 0; j < 8; ++j) {
    const bf16x8 v = rp8[j * 64 + lane];
    const int ib = (j * 64 + lane) * 8;
#pragma unroll
    for (int e = 0; e < 8; ++e)
      INS4(KEY(bf2f((unsigned short)v[e]), ib + e));
  }

  auto bisect = [&]() -> unsigned long long {
    unsigned long long T = 0;
#pragma unroll 1
    for (int b = 63; b >= 32; --b) {
      const unsigned long long Tp = T | (1ULL << b);
      const int cnt = __popcll(__ballot(k1 >= Tp)) + __popcll(__ballot(k2 >= Tp)) +
                      __popcll(__ballot(k3 >= Tp)) + __popcll(__ballot(k4 >= Tp)) +
                      __popcll(__ballot(k5 >= Tp)) + __popcll(__ballot(k6 >= Tp)) +
                      __popcll(__ballot(k7 >= Tp)) + __popcll(__ballot(k8 >= Tp));
      if (cnt >= NSEL) T = Tp;
    }
#pragma unroll 1
    for (int b = 11; b >= 0; --b) {
      const unsigned long long Tp = T | (1ULL << b);
      const int cnt = __popcll(__ballot(k1 >= Tp)) + __popcll(__ballot(k2 >= Tp)) +
                      __popcll(__ballot(k3 >= Tp)) + __popcll(__ballot(k4 >= Tp)) +
                      __popcll(__ballot(k5 >= Tp)) + __popcll(__ballot(k6 >= Tp)) +
                      __popcll(__ballot(k7 >= Tp)) + __popcll(__ballot(k8 >= Tp));
      if (cnt >= NSEL) T = Tp;
    }
    return T;
  };

  unsigned long long T = bisect();

  if (__any(k4 >= T)) {
    if (k4 >= T) {  // suspect lanes build their next-4 (keys < k4)
      const unsigned long long kmin = k4;
#pragma unroll 1
      for (int j = 0; j < 8; ++j) {
        const bf16x8 v = rp8[j * 64 + lane];
        const int ib = (j * 64 + lane) * 8;
#pragma unroll
        for (int e = 0; e < 8; ++e) {
          const unsigned long long kk = KEY(bf2f((unsigned short)v[e]), ib + e);
          if (kk < kmin) INS8(kk);
        }
      }
    }
    T = bisect();
    if (__any(k8 >= T)) {
      // exact serial fallback (rare): 64 ordered extractions
      unsigned long long W = ~0ULL;
      int outi = 0;
#pragma unroll 1
      for (int it = 0; it < NSEL; ++it) {
        unsigned long long best = 0;
        for (int j = 0; j < 8; ++j) {
          const bf16x8 v = rp8[j * 64 + lane];
          const int ib = (j * 64 + lane) * 8;
#pragma unroll
          for (int e = 0; e < 8; ++e) {
            const unsigned long long kk = KEY(bf2f((unsigned short)v[e]), ib + e);
            if (kk < W && kk > best) best = kk;
          }
        }
#pragma unroll
        for (int off = 32; off; off >>= 1) {
          const unsigned long long o = __shfl_xor(best, off);
          if (o > best) best = o;
        }
        if (lane == it) outi = NN - 1 - (int)(best & 0xFFFFFFFFu);
        W = best;
      }
      cand[(size_t)r * NSEL + lane] = outi;
      return;
    }
  }

  // emission: keys >= T (exactly 64), arbitrary order
  const unsigned long long m1 = __ballot(k1 >= T), m2 = __ballot(k2 >= T);
  const unsigned long long m3 = __ballot(k3 >= T), m4 = __ballot(k4 >= T);
  const unsigned long long m5 = __ballot(k5 >= T), m6 = __ballot(k6 >= T);
  const unsigned long long m7 = __ballot(k7 >= T), m8 = __ballot(k8 >= T);

  auto mb = [](unsigned long long m) -> int {
    return (int)__builtin_amdgcn_mbcnt_hi(
        (unsigned)(m >> 32), __builtin_amdgcn_mbcnt_lo((unsigned)m, 0));
  };
  const int c1 = __popcll(m1), c2 = __popcll(m2), c3 = __popcll(m3);
  const int c4 = __popcll(m4), c5 = __popcll(m5), c6 = __popcll(m6);
  const int c7 = __popcll(m7);
  const int b2 = c1, b3 = b2 + c2, b4 = b3 + c3, b5 = b4 + c4;
  const int b6 = b5 + c5, b7 = b6 + c6, b8 = b7 + c7;

  int* cp = cand + (size_t)r * NSEL;
  if (k1 >= T) cp[     mb(m1)] = NN - 1 - (int)(k1 & 0xFFFFFFFFu);
  if (k2 >= T) cp[b2 + mb(m2)] = NN - 1 - (int)(k2 & 0xFFFFFFFFu);
  if (k3 >= T) cp[b3 + mb(m3)] = NN - 1 - (int)(k3 & 0xFFFFFFFFu);
  if (k4 >= T) cp[b4 + mb(m4)] = NN - 1 - (int)(k4 & 0xFFFFFFFFu);
  if (k5 >= T) cp[b5 + mb(m5)] = NN - 1 - (int)(k5 & 0xFFFFFFFFu);
  if (k6 >= T) cp[b6 + mb(m6)] = NN - 1 - (int)(k6 & 0xFFFFFFFFu);
  if (k7 >= T) cp[b7 + mb(m7)] = NN - 1 - (int)(k7 & 0xFFFFFFFFu);
  if (k8 >= T) cp[b8 + mb(m8)] = NN - 1 - (int)(k8 & 0xFFFFFFFFu);
#undef INS4
#undef INS8
#undef KEY
}

// ---------------------------------------------------------------------------
// K1c: exact refine, coalesced (interleaved segments). One block per row;
// 4 lanes/candidate, lane s reads float4 idx j*4+s -> 64B contiguous per
// candidate per instruction. Wave 0: exact top-32-of-64 + softmax + emit.
// ---------------------------------------------------------------------------
__global__ __launch_bounds__(256) void k_refine(
    const float* __restrict__ n1, const float* __restrict__ n2,
    const int* __restrict__ cand,
    float* __restrict__ probs, int* __restrict__ pidx) {
  __shared__ float a_sh[HH];
  __shared__ float cv[NSEL];
  __shared__ int ci[NSEL];
  const int r = blockIdx.x;
  const int tid = threadIdx.x;

  a_sh[tid] = n1[(size_t)r * HH + tid];
  const int c = cand[(size_t)r * NSEL + (tid >> 2)];
  __syncthreads();

  const int s = tid & 3;  // interleave: float4 index j*4+s
  const float4* br = reinterpret_cast<const float4*>(n2 + (size_t)c * HH);
  const float4* ar = reinterpret_cast<const float4*>(a_sh);
  float a0 = 0.f, a1 = 0.f, a2 = 0.f, a3 = 0.f;
#pragma unroll
  for (int j = 0; j < 16; j += 4) {
    const float4 bx = br[(j + 0) * 4 + s];
    const float4 by = br[(j + 1) * 4 + s];
    const float4 bz = br[(j + 2) * 4 + s];
    const float4 bw = br[(j + 3) * 4 + s];
    const float4 ax = ar[(j + 0) * 4 + s];
    const float4 ay = ar[(j + 1) * 4 + s];
    const float4 az = ar[(j + 2) * 4 + s];
    const float4 aw = ar[(j + 3) * 4 + s];
    a0 = fmaf(ax.x, bx.x, fmaf(ax.y, bx.y, fmaf(ax.z, bx.z, fmaf(ax.w, bx.w, a0))));
    a1 = fmaf(ay.x, by.x, fmaf(ay.y, by.y, fmaf(ay.z, by.z, fmaf(ay.w, by.w, a1))));
    a2 = fmaf(az.x, bz.x, fmaf(az.y, bz.y, fmaf(az.z, bz.z, fmaf(az.w, bz.w, a2))));
    a3 = fmaf(aw.x, bw.x, fmaf(aw.y, bw.y, fmaf(aw.z, bw.z, fmaf(aw.w, bw.w, a3))));
  }
  float acc = (a0 + a1) + (a2 + a3);
  acc += __shfl_xor(acc, 1);
  acc += __shfl_xor(acc, 2);
  if ((tid & 3) == 0) { cv[tid >> 2] = acc; ci[tid >> 2] = c; }
  __syncthreads();

  if (tid < NSEL) {  // wave 0: lane = candidate
    const float v = cv[tid];
    const int cc = ci[tid];
    const unsigned long long key =
        (((unsigned long long)__float_as_uint(v)) << 32) | (unsigned)(NN - 1 - cc);

    unsigned long long T = 0;
#pragma unroll 1
    for (int b = 63; b >= 32; --b) {
      const unsigned long long Tp = T | (1ULL << b);
      if (__popcll(__ballot(key >= Tp)) >= TOPK) T = Tp;
    }
#pragma unroll 1
    for (int b = 11; b >= 0; --b) {
      const unsigned long long Tp = T | (1ULL << b);
      if (__popcll(__ballot(key >= Tp)) >= TOPK) T = Tp;
    }

    const bool win = (key >= T);  // exactly 32 lanes
    float mx = v;
#pragma unroll
    for (int off = 32; off; off >>= 1) mx = fmaxf(mx, __shfl_xor(mx, off));
    const float e = win ? expf(v - mx) : 0.f;
    float sum = e;
#pragma unroll
    for (int off = 32; off; off >>= 1) sum += __shfl_xor(sum, off);

    const unsigned long long wm = __ballot(win);
    if (win) {
      const int slot = (int)__builtin_amdgcn_mbcnt_hi(
          (unsigned)(wm >> 32), __builtin_amdgcn_mbcnt_lo((unsigned)wm, 0));
      probs[(size_t)r * TOPK + slot] = e / sum;
      pidx [(size_t)r * TOPK + slot] = cc;
    }
  }
}

// ---------------------------------------------------------------------------
// K3: ff1 = relu(tgt1 @ w1^T + b1). A reg-staged from row-major bf16 t1b16,
// B via gload16 from w1pack. bf16 row-major out. grid 512.
// ---------------------------------------------------------------------------
__global__ __launch_bounds__(256) void k_ffgemm1_pk(
    const unsigned short* __restrict__ Ab16,
    const unsigned short* __restrict__ wpk,
    const float* __restrict__ bias,
    unsigned short* __restrict__ Cb) {
  __shared__ __align__(16) unsigned short Al[512 * 8];
  __shared__ __align__(16) unsigned short Bl[512 * 8];
  const int tid = threadIdx.x;
  const int lane = tid & 63, wid = tid >> 6;
  const int wr = wid >> 1, wc = wid & 1;
  const int bm = blockIdx.x >> 1, bn = blockIdx.x & 1;
  const int m0 = bm * 128, n0 = bn * 128;

  f32x4 acc[4][4];
#pragma unroll
  for (int i = 0; i < 4; ++i)
#pragma unroll
    for (int j = 0; j < 4; ++j) acc[i][j] = (f32x4){0.f, 0.f, 0.f, 0.f};

  unsigned short* lB0 = Bl + (size_t)(wid * 64) * 8;
  unsigned short* lB1 = Bl + (size_t)(256 + wid * 64) * 8;
  const int row0 = tid & 127, g0 = tid >> 7, g1 = g0 + 2;

  for (int t = 0; t < 8; ++t) {
    const unsigned short* gw = wpk + (size_t)(bn * 8 + t) * 4096;
    __syncthreads();
    const uint4 a0 = *reinterpret_cast<const uint4*>(
        Ab16 + (size_t)(m0 + row0) * HH + t * 32 + g0 * 8);
    const uint4 a1 = *reinterpret_cast<const uint4*>(
        Ab16 + (size_t)(m0 + row0) * HH + t * 32 + g1 * 8);
    *reinterpret_cast<uint4*>(Al + (size_t)tid * 8) = a0;
    *reinterpret_cast<uint4*>(Al + (size_t)(256 + tid) * 8) = a1;
    gload16(gw + (size_t)tid * 8, lB0);
    gload16(gw + (size_t)(256 + tid) * 8, lB1);
    __syncthreads();
    mfma_tile(Al, Bl, wr, wc, lane, acc);
  }

  const int crow = m0 + wr * 64 + (lane >> 4) * 4;
  const int ccol = n0 + wc * 64 + (lane & 15);
#pragma unroll
  for (int i = 0; i < 4; ++i)
#pragma unroll
    for (int j = 0; j < 4; ++j) {
      const float bv = bias[ccol + j * 16];
      unsigned short* cp = Cb + (size_t)(crow + i * 16) * HH + ccol + j * 16;
#pragma unroll
      for (int q = 0; q < 4; ++q)
        cp[(size_t)q * HH] = f2bf(fmaxf(acc[i][j][q] + bv, 0.f));
    }
}

// ---------------------------------------------------------------------------
// K4: ff2 = ff1 @ w2^T + b2. A reg-staged from row-major bf16, B gload16.
// ---------------------------------------------------------------------------
__global__ __launch_bounds__(256) void k_ffgemm2_pk(
    const unsigned short* __restrict__ Ab16,
    const unsigned short* __restrict__ wpk,
    const float* __restrict__ bias,
    float* __restrict__ C) {
  __shared__ __align__(16) unsigned short Al[512 * 8];
  __shared__ __align__(16) unsigned short Bl[512 * 8];
  const int tid = threadIdx.x;
  const int lane = tid & 63, wid = tid >> 6;
  const int wr = wid >> 1, wc = wid & 1;
  const int bm = blockIdx.x >> 1, bn = blockIdx.x & 1;
  const int m0 = bm * 128, n0 = bn * 128;

  f32x4 acc[4][4];
#pragma unroll
  for (int i = 0; i < 4; ++i)
#pragma unroll
    for (int j = 0; j < 4; ++j) acc[i][j] = (f32x4){0.f, 0.f, 0.f, 0.f};

  unsigned short* lB0 = Bl + (size_t)(wid * 64) * 8;
  unsigned short* lB1 = Bl + (size_t)(256 + wid * 64) * 8;
  const int row0 = tid & 127, g0 = tid >> 7, g1 = g0 + 2;

  for (int t = 0; t < 8; ++t) {
    const unsigned short* gw = wpk + (size_t)(bn * 8 + t) * 4096;
    __syncthreads();
    const uint4 a0 = *reinterpret_cast<const uint4*>(
        Ab16 + (size_t)(m0 + row0) * HH + t * 32 + g0 * 8);
    const uint4 a1 = *reinterpret_cast<const uint4*>(
        Ab16 + (size_t)(m0 + row0) * HH + t * 32 + g1 * 8);
    *reinterpret_cast<uint4*>(Al + (size_t)tid * 8) = a0;
    *reinterpret_cast<uint4*>(Al + (size_t)(256 + tid) * 8) = a1;
    gload16(gw + (size_t)tid * 8, lB0);
    gload16(gw + (size_t)(256 + tid) * 8, lB1);
    __syncthreads();
    mfma_tile(Al, Bl, wr, wc, lane, acc);
  }

  const int crow = m0 + wr * 64 + (lane >> 4) * 4;
  const int ccol = n0 + wc * 64 + (lane & 15);
#pragma unroll
  for (int i = 0; i < 4; ++i)
#pragma unroll
    for (int j = 0; j < 4; ++j) {
      const float bv = bias[ccol + j * 16];
      float* cp = C + (size_t)(crow + i * 16) * HH + ccol + j * 16;
#pragma unroll
      for (int q = 0; q < 4; ++q) cp[(size_t)q * HH] = acc[i][j][q] + bv;
    }
}

// ---------------------------------------------------------------------------
// K2: gc gather (bf16 src) + residual + LN1 -> t1b16 (bf16 row-major).
// Single-batch blocks, grid (512, 8) x-major. launch_bounds(256,8) caps
// VGPR at 64 (R17 measured 112 -> occ 17%); R11's near-identical loop
// compiled to 44 VGPR, so no spill expected.
// ---------------------------------------------------------------------------
__global__ __launch_bounds__(256, 8) void k_gather_ln1(
    const unsigned short* __restrict__ s16, const float* __restrict__ tgt,
    const float* __restrict__ probs, const int* __restrict__ pidx,
    const float* __restrict__ lnw, const float* __restrict__ lnb,
    unsigned short* __restrict__ t1b16) {
  __shared__ float lp[8][TOPK];
  __shared__ int li[8][TOPK];
  const int mt = blockIdx.x, b = blockIdx.y;
  const int tid = threadIdx.x;
  const int mloc = tid >> 5, kg = tid & 31, h8 = kg * 8;
  const int m = mt * 8 + mloc;
  lp[mloc][kg] = probs[(size_t)m * TOPK + kg];
  li[mloc][kg] = pidx[(size_t)m * TOPK + kg];
  __syncthreads();

  const unsigned short* sb = s16 + (size_t)b * NN * HH + h8;

  float acc[8] = {0.f, 0.f, 0.f, 0.f, 0.f, 0.f, 0.f, 0.f};
#pragma unroll
  for (int k = 0; k < TOPK; ++k) {
    const bf16x8 v = *reinterpret_cast<const bf16x8*>(sb + (size_t)li[mloc][k] * HH);
    const float p = lp[mloc][k];
#pragma unroll
    for (int e = 0; e < 8; ++e)
      acc[e] = fmaf(p, bf2f((unsigned short)v[e]), acc[e]);
  }

  const size_t obase = ((size_t)b * NN + m) * HH + h8;
  const float4 t0 = *reinterpret_cast<const float4*>(tgt + obase);
  const float4 t1 = *reinterpret_cast<const float4*>(tgt + obase + 4);
  acc[0] += t0.x; acc[1] += t0.y; acc[2] += t0.z; acc[3] += t0.w;
  acc[4] += t1.x; acc[5] += t1.y; acc[6] += t1.z; acc[7] += t1.w;

  float s = 0.f, s2 = 0.f;
#pragma unroll
  for (int e = 0; e < 8; ++e) { s += acc[e]; s2 = fmaf(acc[e], acc[e], s2); }
#pragma unroll
  for (int off = 16; off; off >>= 1) {
    s += __shfl_xor(s, off, 32);
    s2 += __shfl_xor(s2, off, 32);
  }
  const float mu = s * (1.f / HH);
  const float var = s2 * (1.f / HH) - mu * mu;
  const float rs = rsqrtf(var + LN_EPS);

  const float4 w0 = *reinterpret_cast<const float4*>(lnw + h8);
  const float4 w1 = *reinterpret_cast<const float4*>(lnw + h8 + 4);
  const float4 c0 = *reinterpret_cast<const float4*>(lnb + h8);
  const float4 c1 = *reinterpret_cast<const float4*>(lnb + h8 + 4);
  const float wv[8] = {w0.x, w0.y, w0.z, w0.w, w1.x, w1.y, w1.z, w1.w};
  const float cv[8] = {c0.x, c0.y, c0.z, c0.w, c1.x, c1.y, c1.z, c1.w};
  union { unsigned short us[8]; uint4 q; } ot;
#pragma unroll
  for (int e = 0; e < 8; ++e)
    ot.us[e] = f2bf((acc[e] - mu) * rs * wv[e] + cv[e]);
  *reinterpret_cast<uint4*>(t1b16 + obase) = ot.q;
}

// ---------------------------------------------------------------------------
// K5: out = LN2(t1b16 + ff2) -> d_out (fp32). 8 rows/block, 32 lanes/row.
// ---------------------------------------------------------------------------
__global__ __launch_bounds__(256) void k_res_ln2(
    const unsigned short* __restrict__ t1b16, const float* __restrict__ ff,
    const float* __restrict__ lnw, const float* __restrict__ lnb,
    float* __restrict__ out) {
  const int tid = threadIdx.x;
  const int rloc = tid >> 5, kg = tid & 31, h8 = kg * 8;
  const size_t row = (size_t)blockIdx.x * 8 + rloc;
  const size_t obase = row * HH + h8;

  const bf16x8 t = *reinterpret_cast<const bf16x8*>(t1b16 + obase);
  const float4 f0 = *reinterpret_cast<const float4*>(ff + obase);
  const float4 f1 = *reinterpret_cast<const float4*>(ff + obase + 4);
  float x[8];
  x[0] = bf2f((unsigned short)t[0]) + f0.x;
  x[1] = bf2f((unsigned short)t[1]) + f0.y;
  x[2] = bf2f((unsigned short)t[2]) + f0.z;
  x[3] = bf2f((unsigned short)t[3]) + f0.w;
  x[4] = bf2f((unsigned short)t[4]) + f1.x;
  x[5] = bf2f((unsigned short)t[5]) + f1.y;
  x[6] = bf2f((unsigned short)t[6]) + f1.z;
  x[7] = bf2f((unsigned short)t[7]) + f1.w;

  float s = 0.f, s2 = 0.f;
#pragma unroll
  for (int e = 0; e < 8; ++e) { s += x[e]; s2 = fmaf(x[e], x[e], s2); }
#pragma unroll
  for (int off = 16; off; off >>= 1) {
    s += __shfl_xor(s, off, 32);
    s2 += __shfl_xor(s2, off, 32);
  }
  const float mu = s * (1.f / HH);
  const float var = s2 * (1.f / HH) - mu * mu;
  const float rs = rsqrtf(var + LN_EPS);

  const float4 w0 = *reinterpret_cast<const float4*>(lnw + h8);
  const float4 w1 = *reinterpret_cast<const float4*>(lnw + h8 + 4);
  const float4 c0 = *reinterpret_cast<const float4*>(lnb + h8);
  const float4 c1 = *reinterpret_cast<const float4*>(lnb + h8 + 4);
  float4 o0, o1;
  o0.x = (x[0] - mu) * rs * w0.x + c0.x;
  o0.y = (x[1] - mu) * rs * w0.y + c0.y;
  o0.z = (x[2] - mu) * rs * w0.z + c0.z;
  o0.w = (x[3] - mu) * rs * w0.w + c0.w;
  o1.x = (x[4] - mu) * rs * w1.x + c1.x;
  o1.y = (x[5] - mu) * rs * w1.y + c1.y;
  o1.z = (x[6] - mu) * rs * w1.z + c1.z;
  o1.w = (x[7] - mu) * rs * w1.w + c1.w;
  *reinterpret_cast<float4*>(out + obase) = o0;
  *reinterpret_cast<float4*>(out + obase + 4) = o1;
}

// ---------------------------------------------------------------------------
extern "C" void kernel_launch(void* const* d_in, const int* in_sizes, int n_in,
                              void* d_out, int out_size, void* d_ws, size_t ws_size,
                              hipStream_t stream) {
  const float* src  = (const float*)d_in[0];
  const float* tgt  = (const float*)d_in[1];
  const float* n1   = (const float*)d_in[2];
  const float* n2   = (const float*)d_in[3];
  const float* w1   = (const float*)d_in[4];
  const float* b1   = (const float*)d_in[5];
  const float* w2   = (const float*)d_in[6];
  const float* b2   = (const float*)d_in[7];
  const float* ln1w = (const float*)d_in[8];
  const float* ln1b = (const float*)d_in[9];
  const float* ln2w = (const float*)d_in[10];
  const float* ln2b = (const float*)d_in[11];
  float* out = (float*)d_out;

  // ws: probs(512K) | pidx(512K) | 64MiB region | apack 2M | bpack 2M
  //     | wpacks 256K @68M | cand 1M @69M
  // region lifetime interval map (byte offsets; audited):
  //   adjb   [0,32M)   adjgemm -> topk64 (bf16; dead before srcpack)
  //   s16    [0,16M)   srcpack -> gather (dead before ffgemm2)
  //   ff1b16 [32,48M)  ffgemm1 -> ffgemm2
  //   t1b16  [48,64M)  gather -> ffgemm1 + res_ln2
  //   ff2    [0,32M)   ffgemm2 -> res_ln2 (overlaps only dead s16/adjb)
  //   cand @69M: topk64 -> refine (outside the 64M region; no conflicts)
  float* wsf   = (float*)d_ws;
  float* probs = wsf;
  int*   pidx  = (int*)(wsf + (size_t)NN * TOPK);
  char*  cbase = (char*)(wsf + 2 * (size_t)NN * TOPK);
  unsigned short* adjb   = (unsigned short*)cbase;
  unsigned short* s16    = (unsigned short*)cbase;
  unsigned short* ff1b16 = (unsigned short*)(cbase + ((size_t)32 << 20));
  unsigned short* t1b16  = (unsigned short*)(cbase + ((size_t)48 << 20));
  float* ff2   = (float*)cbase;
  unsigned short* apack  = (unsigned short*)(cbase + ((size_t)64 << 20));
  unsigned short* bpack  = (unsigned short*)(cbase + ((size_t)66 << 20));
  unsigned short* w1pack = (unsigned short*)(cbase + ((size_t)68 << 20));
  unsigned short* w2pack = w1pack + 65536;
  int* cand = (int*)(cbase + ((size_t)69 << 20));

  dim3 gp(512, 2);
  k_pack<<<gp, 256, 0, stream>>>(n1, n2, apack, bpack);
  k_adjgemm_pk<<<(NN / 128) * (NN / 128), 256, 0, stream>>>(apack, bpack, adjb);
  k_topk64<<<NN / 4, 256, 0, stream>>>(adjb, cand);
  k_refine<<<NN, 256, 0, stream>>>(n1, n2, cand, probs, pidx);

  k_srcpack<<<(BATCH * NN * HH) / (256 * 8), 256, 0, stream>>>(src, s16);
  dim3 gw(32, 2);
  k_packw<<<gw, 256, 0, stream>>>(w1, w2, w1pack, w2pack);

  dim3 gg(NN / 8, BATCH);  // single-batch blocks, x-major (L2 slab residency)
  k_gather_ln1<<<gg, 256, 0, stream>>>(s16, tgt, probs, pidx, ln1w, ln1b, t1b16);

  const int gemm_grid = (BATCH * NN / 128) * (HH / 128);  // 512
  k_ffgemm1_pk<<<gemm_grid, 256, 0, stream>>>(t1b16, w1pack, b1, ff1b16);
  k_ffgemm2_pk<<<gemm_grid, 256, 0, stream>>>(ff1b16, w2pack, b2, ff2);

  k_res_ln2<<<BATCH * NN / 8, 256, 0, stream>>>(t1b16, ff2, ln2w, ln2b, out);
}

// Round 19
// 157.994 us; speedup vs baseline: 2.7167x; 2.7167x over previous
//
#include <hip/hip_runtime.h>
#include <math.h>

#define NN 4096
#define HH 256
#define BATCH 8
#define TOPK 32
#define NSEL 64
#define LN_EPS 1e-5f

typedef float f32x4 __attribute__((ext_vector_type(4)));
typedef short bf16x8 __attribute__((ext_vector_type(8)));

__device__ __forceinline__ unsigned short f2bf(float x) {
  unsigned u = __float_as_uint(x);
  u += 0x7FFF + ((u >> 16) & 1);  // RNE
  return (unsigned short)(u >> 16);
}
__device__ __forceinline__ float bf2f(unsigned short h) {
  return __uint_as_float(((unsigned)h) << 16);
}

// async global->LDS, 16B per lane; LDS dest is wave-uniform base + lane*16
__device__ __forceinline__ void gload16(const void* g, void* l) {
  __builtin_amdgcn_global_load_lds(
      (const __attribute__((address_space(1))) void*)g,
      (__attribute__((address_space(3))) void*)l, 16, 0, 0);
}

// one BK=32 K-step: 4x4 fragment MFMAs from [g:4][row:128][8] LDS tiles
__device__ __forceinline__ void mfma_tile(const unsigned short* Al,
                                          const unsigned short* Bl,
                                          int wr, int wc, int lane,
                                          f32x4 acc[4][4]) {
  const int g = lane >> 4, r = lane & 15;
  bf16x8 a[4], b[4];
#pragma unroll
  for (int i = 0; i < 4; ++i)
    a[i] = *reinterpret_cast<const bf16x8*>(Al + ((size_t)(g * 128 + wr * 64 + i * 16 + r)) * 8);
#pragma unroll
  for (int j = 0; j < 4; ++j)
    b[j] = *reinterpret_cast<const bf16x8*>(Bl + ((size_t)(g * 128 + wc * 64 + j * 16 + r)) * 8);
#pragma unroll
  for (int i = 0; i < 4; ++i)
#pragma unroll
    for (int j = 0; j < 4; ++j)
      acc[i][j] = __builtin_amdgcn_mfma_f32_16x16x32_bf16(a[i], b[j], acc[i][j], 0, 0, 0);
}

// ---------------------------------------------------------------------------
// K0: bf16 (hi-only) pack of n1/n2 into GEMM LDS slot order. 8 K-steps.
// ---------------------------------------------------------------------------
__global__ __launch_bounds__(256) void k_pack(
    const float* __restrict__ n1, const float* __restrict__ n2,
    unsigned short* __restrict__ apack, unsigned short* __restrict__ bpack) {
  const int u = blockIdx.x * 256 + threadIdx.x;  // 0..131071
  const float* srcm = blockIdx.y ? n2 : n1;
  unsigned short* dstm = blockIdx.y ? bpack : apack;
  const int row = u >> 5, kg = u & 31;
  const int st = kg >> 2, g = kg & 3;
  const int bm = row >> 7, slot = g * 128 + (row & 127);

  const float4 v0 = *reinterpret_cast<const float4*>(srcm + (size_t)row * HH + kg * 8);
  const float4 v1 = *reinterpret_cast<const float4*>(srcm + (size_t)row * HH + kg * 8 + 4);
  const float xs[8] = {v0.x, v0.y, v0.z, v0.w, v1.x, v1.y, v1.z, v1.w};
  union { unsigned short s[8]; uint4 q; } hi;
#pragma unroll
  for (int e = 0; e < 8; ++e) hi.s[e] = f2bf(xs[e]);
  *reinterpret_cast<uint4*>(dstm + ((size_t)(bm * 8 + st) * 512 + slot) * 8) = hi.q;
}

// ---------------------------------------------------------------------------
// K0b: src fp32 -> bf16 (same [b][n][h] layout). Runs AFTER k_topk64.
// ---------------------------------------------------------------------------
__global__ __launch_bounds__(256) void k_srcpack(
    const float* __restrict__ src, unsigned short* __restrict__ s16) {
  const size_t i = ((size_t)blockIdx.x * 256 + threadIdx.x) * 8;
  const float4 v0 = *reinterpret_cast<const float4*>(src + i);
  const float4 v1 = *reinterpret_cast<const float4*>(src + i + 4);
  const float xs[8] = {v0.x, v0.y, v0.z, v0.w, v1.x, v1.y, v1.z, v1.w};
  union { unsigned short s[8]; uint4 q; } p;
#pragma unroll
  for (int e = 0; e < 8; ++e) p.s[e] = f2bf(xs[e]);
  *reinterpret_cast<uint4*>(s16 + i) = p.q;
}

// ---------------------------------------------------------------------------
// K0c: w1/w2 [256][256] fp32 -> bf16 GEMM slot-order packs.
// ---------------------------------------------------------------------------
__global__ __launch_bounds__(256) void k_packw(
    const float* __restrict__ w1, const float* __restrict__ w2,
    unsigned short* __restrict__ w1pack, unsigned short* __restrict__ w2pack) {
  const int u = blockIdx.x * 256 + threadIdx.x;  // 0..8191
  const float* srcm = blockIdx.y ? w2 : w1;
  unsigned short* dstm = blockIdx.y ? w2pack : w1pack;
  const int row = u >> 5, kg = u & 31;
  const int st = kg >> 2, g = kg & 3;
  const int bn = row >> 7, slot = g * 128 + (row & 127);

  const float4 v0 = *reinterpret_cast<const float4*>(srcm + (size_t)row * HH + kg * 8);
  const float4 v1 = *reinterpret_cast<const float4*>(srcm + (size_t)row * HH + kg * 8 + 4);
  const float xs[8] = {v0.x, v0.y, v0.z, v0.w, v1.x, v1.y, v1.z, v1.w};
  union { unsigned short s[8]; uint4 q; } p;
#pragma unroll
  for (int e = 0; e < 8; ++e) p.s[e] = f2bf(xs[e]);
  *reinterpret_cast<uint4*>(dstm + ((size_t)(bn * 8 + st) * 512 + slot) * 8) = p.q;
}

// ---------------------------------------------------------------------------
// K1a: adjb ~= bf16(n1 @ n2^T), ONE bf16 phase. Selection-only values:
// storage rounding (+-0.125) + GEMM bf16 error both << v32-v64 gap (~0.93);
// exact values recomputed by k_refine. 8 K-steps, XCD-swizzled. grid 1024.
// ---------------------------------------------------------------------------
__global__ __launch_bounds__(256) void k_adjgemm_pk(
    const unsigned short* __restrict__ apack,
    const unsigned short* __restrict__ bpack,
    unsigned short* __restrict__ adjb) {
  __shared__ __align__(16) unsigned short Al[512 * 8];
  __shared__ __align__(16) unsigned short Bl[512 * 8];
  const int tid = threadIdx.x;
  const int lane = tid & 63, wid = tid >> 6;
  const int wr = wid >> 1, wc = wid & 1;
  const int wgid = (blockIdx.x & 7) * 128 + (blockIdx.x >> 3);  // XCD swizzle
  const int bm = wgid >> 5, bn = wgid & 31;
  const int m0 = bm * 128, n0 = bn * 128;

  f32x4 acc[4][4];
#pragma unroll
  for (int i = 0; i < 4; ++i)
#pragma unroll
    for (int j = 0; j < 4; ++j) acc[i][j] = (f32x4){0.f, 0.f, 0.f, 0.f};

  unsigned short* lA0 = Al + (size_t)(wid * 64) * 8;
  unsigned short* lA1 = Al + (size_t)(256 + wid * 64) * 8;
  unsigned short* lB0 = Bl + (size_t)(wid * 64) * 8;
  unsigned short* lB1 = Bl + (size_t)(256 + wid * 64) * 8;

  for (int t = 0; t < 8; ++t) {
    const unsigned short* ga = apack + (size_t)(bm * 8 + t) * 4096;
    const unsigned short* gb = bpack + (size_t)(bn * 8 + t) * 4096;
    __syncthreads();
    gload16(ga + (size_t)tid * 8, lA0);
    gload16(ga + (size_t)(256 + tid) * 8, lA1);
    gload16(gb + (size_t)tid * 8, lB0);
    gload16(gb + (size_t)(256 + tid) * 8, lB1);
    __syncthreads();
    mfma_tile(Al, Bl, wr, wc, lane, acc);
  }

  const int crow = m0 + wr * 64 + (lane >> 4) * 4;
  const int ccol = n0 + wc * 64 + (lane & 15);
#pragma unroll
  for (int i = 0; i < 4; ++i)
#pragma unroll
    for (int j = 0; j < 4; ++j) {
      unsigned short* cp = adjb + (size_t)(crow + i * 16) * NN + ccol + j * 16;
#pragma unroll
      for (int q = 0; q < 4; ++q) cp[(size_t)q * NN] = f2bf(acc[i][j][q]);
    }
}

// ---------------------------------------------------------------------------
// K1b: per-row approx top-64 candidate indices via ballot-bisection, from
// the bf16 adj (half the scan traffic). Keys unique via idx field.
// ---------------------------------------------------------------------------
__global__ __launch_bounds__(256) void k_topk64(
    const unsigned short* __restrict__ adjb, int* __restrict__ cand) {
  const int tid = threadIdx.x;
  const int wid = tid >> 6, lane = tid & 63;
  const int r = blockIdx.x * 4 + wid;
  const bf16x8* rp8 = reinterpret_cast<const bf16x8*>(adjb + (size_t)r * NN);

#define KEY(v, ix) ((((unsigned long long)__float_as_uint(v)) << 32) | \
                    (unsigned)(NN - 1 - (ix)))

  unsigned long long k1 = 0, k2 = 0, k3 = 0, k4 = 0;
  unsigned long long k5 = 0, k6 = 0, k7 = 0, k8 = 0;

#define INS4(kk)                                              \
  do { const unsigned long long _k = (kk);                    \
    if (_k > k4) {                                            \
      if (_k > k1)      { k4 = k3; k3 = k2; k2 = k1; k1 = _k; } \
      else if (_k > k2) { k4 = k3; k3 = k2; k2 = _k; }        \
      else if (_k > k3) { k4 = k3; k3 = _k; }                 \
      else              { k4 = _k; } } } while (0)
#define INS8(kk)                                              \
  do { const unsigned long long _k = (kk);                    \
    if (_k > k8) {                                            \
      if (_k > k5)      { k8 = k7; k7 = k6; k6 = k5; k5 = _k; } \
      else if (_k > k6) { k8 = k7; k7 = k6; k6 = _k; }        \
      else if (_k > k7) { k8 = k7; k7 = _k; }                 \
      else              { k8 = _k; } } } while (0)

#pragma unroll
  for (int j = 0; j < 8; ++j) {
    const bf16x8 v = rp8[j * 64 + lane];
    const int ib = (j * 64 + lane) * 8;
#pragma unroll
    for (int e = 0; e < 8; ++e)
      INS4(KEY(bf2f((unsigned short)v[e]), ib + e));
  }

  auto bisect = [&]() -> unsigned long long {
    unsigned long long T = 0;
#pragma unroll 1
    for (int b = 63; b >= 32; --b) {
      const unsigned long long Tp = T | (1ULL << b);
      const int cnt = __popcll(__ballot(k1 >= Tp)) + __popcll(__ballot(k2 >= Tp)) +
                      __popcll(__ballot(k3 >= Tp)) + __popcll(__ballot(k4 >= Tp)) +
                      __popcll(__ballot(k5 >= Tp)) + __popcll(__ballot(k6 >= Tp)) +
                      __popcll(__ballot(k7 >= Tp)) + __popcll(__ballot(k8 >= Tp));
      if (cnt >= NSEL) T = Tp;
    }
#pragma unroll 1
    for (int b = 11; b >= 0; --b) {
      const unsigned long long Tp = T | (1ULL << b);
      const int cnt = __popcll(__ballot(k1 >= Tp)) + __popcll(__ballot(k2 >= Tp)) +
                      __popcll(__ballot(k3 >= Tp)) + __popcll(__ballot(k4 >= Tp)) +
                      __popcll(__ballot(k5 >= Tp)) + __popcll(__ballot(k6 >= Tp)) +
                      __popcll(__ballot(k7 >= Tp)) + __popcll(__ballot(k8 >= Tp));
      if (cnt >= NSEL) T = Tp;
    }
    return T;
  };

  unsigned long long T = bisect();

  if (__any(k4 >= T)) {
    if (k4 >= T) {  // suspect lanes build their next-4 (keys < k4)
      const unsigned long long kmin = k4;
#pragma unroll 1
      for (int j = 0; j < 8; ++j) {
        const bf16x8 v = rp8[j * 64 + lane];
        const int ib = (j * 64 + lane) * 8;
#pragma unroll
        for (int e = 0; e < 8; ++e) {
          const unsigned long long kk = KEY(bf2f((unsigned short)v[e]), ib + e);
          if (kk < kmin) INS8(kk);
        }
      }
    }
    T = bisect();
    if (__any(k8 >= T)) {
      // exact serial fallback (rare): 64 ordered extractions
      unsigned long long W = ~0ULL;
      int outi = 0;
#pragma unroll 1
      for (int it = 0; it < NSEL; ++it) {
        unsigned long long best = 0;
        for (int j = 0; j < 8; ++j) {
          const bf16x8 v = rp8[j * 64 + lane];
          const int ib = (j * 64 + lane) * 8;
#pragma unroll
          for (int e = 0; e < 8; ++e) {
            const unsigned long long kk = KEY(bf2f((unsigned short)v[e]), ib + e);
            if (kk < W && kk > best) best = kk;
          }
        }
#pragma unroll
        for (int off = 32; off; off >>= 1) {
          const unsigned long long o = __shfl_xor(best, off);
          if (o > best) best = o;
        }
        if (lane == it) outi = NN - 1 - (int)(best & 0xFFFFFFFFu);
        W = best;
      }
      cand[(size_t)r * NSEL + lane] = outi;
      return;
    }
  }

  // emission: keys >= T (exactly 64), arbitrary order
  const unsigned long long m1 = __ballot(k1 >= T), m2 = __ballot(k2 >= T);
  const unsigned long long m3 = __ballot(k3 >= T), m4 = __ballot(k4 >= T);
  const unsigned long long m5 = __ballot(k5 >= T), m6 = __ballot(k6 >= T);
  const unsigned long long m7 = __ballot(k7 >= T), m8 = __ballot(k8 >= T);

  auto mb = [](unsigned long long m) -> int {
    return (int)__builtin_amdgcn_mbcnt_hi(
        (unsigned)(m >> 32), __builtin_amdgcn_mbcnt_lo((unsigned)m, 0));
  };
  const int c1 = __popcll(m1), c2 = __popcll(m2), c3 = __popcll(m3);
  const int c4 = __popcll(m4), c5 = __popcll(m5), c6 = __popcll(m6);
  const int c7 = __popcll(m7);
  const int b2 = c1, b3 = b2 + c2, b4 = b3 + c3, b5 = b4 + c4;
  const int b6 = b5 + c5, b7 = b6 + c6, b8 = b7 + c7;

  int* cp = cand + (size_t)r * NSEL;
  if (k1 >= T) cp[     mb(m1)] = NN - 1 - (int)(k1 & 0xFFFFFFFFu);
  if (k2 >= T) cp[b2 + mb(m2)] = NN - 1 - (int)(k2 & 0xFFFFFFFFu);
  if (k3 >= T) cp[b3 + mb(m3)] = NN - 1 - (int)(k3 & 0xFFFFFFFFu);
  if (k4 >= T) cp[b4 + mb(m4)] = NN - 1 - (int)(k4 & 0xFFFFFFFFu);
  if (k5 >= T) cp[b5 + mb(m5)] = NN - 1 - (int)(k5 & 0xFFFFFFFFu);
  if (k6 >= T) cp[b6 + mb(m6)] = NN - 1 - (int)(k6 & 0xFFFFFFFFu);
  if (k7 >= T) cp[b7 + mb(m7)] = NN - 1 - (int)(k7 & 0xFFFFFFFFu);
  if (k8 >= T) cp[b8 + mb(m8)] = NN - 1 - (int)(k8 & 0xFFFFFFFFu);
#undef INS4
#undef INS8
#undef KEY
}

// ---------------------------------------------------------------------------
// K1c: exact refine, coalesced (interleaved segments). One block per row;
// 4 lanes/candidate, lane s reads float4 idx j*4+s -> 64B contiguous per
// candidate per instruction. Wave 0: exact top-32-of-64 + softmax + emit.
// ---------------------------------------------------------------------------
__global__ __launch_bounds__(256) void k_refine(
    const float* __restrict__ n1, const float* __restrict__ n2,
    const int* __restrict__ cand,
    float* __restrict__ probs, int* __restrict__ pidx) {
  __shared__ float a_sh[HH];
  __shared__ float cv[NSEL];
  __shared__ int ci[NSEL];
  const int r = blockIdx.x;
  const int tid = threadIdx.x;

  a_sh[tid] = n1[(size_t)r * HH + tid];
  const int c = cand[(size_t)r * NSEL + (tid >> 2)];
  __syncthreads();

  const int s = tid & 3;  // interleave: float4 index j*4+s
  const float4* br = reinterpret_cast<const float4*>(n2 + (size_t)c * HH);
  const float4* ar = reinterpret_cast<const float4*>(a_sh);
  float a0 = 0.f, a1 = 0.f, a2 = 0.f, a3 = 0.f;
#pragma unroll
  for (int j = 0; j < 16; j += 4) {
    const float4 bx = br[(j + 0) * 4 + s];
    const float4 by = br[(j + 1) * 4 + s];
    const float4 bz = br[(j + 2) * 4 + s];
    const float4 bw = br[(j + 3) * 4 + s];
    const float4 ax = ar[(j + 0) * 4 + s];
    const float4 ay = ar[(j + 1) * 4 + s];
    const float4 az = ar[(j + 2) * 4 + s];
    const float4 aw = ar[(j + 3) * 4 + s];
    a0 = fmaf(ax.x, bx.x, fmaf(ax.y, bx.y, fmaf(ax.z, bx.z, fmaf(ax.w, bx.w, a0))));
    a1 = fmaf(ay.x, by.x, fmaf(ay.y, by.y, fmaf(ay.z, by.z, fmaf(ay.w, by.w, a1))));
    a2 = fmaf(az.x, bz.x, fmaf(az.y, bz.y, fmaf(az.z, bz.z, fmaf(az.w, bz.w, a2))));
    a3 = fmaf(aw.x, bw.x, fmaf(aw.y, bw.y, fmaf(aw.z, bw.z, fmaf(aw.w, bw.w, a3))));
  }
  float acc = (a0 + a1) + (a2 + a3);
  acc += __shfl_xor(acc, 1);
  acc += __shfl_xor(acc, 2);
  if ((tid & 3) == 0) { cv[tid >> 2] = acc; ci[tid >> 2] = c; }
  __syncthreads();

  if (tid < NSEL) {  // wave 0: lane = candidate
    const float v = cv[tid];
    const int cc = ci[tid];
    const unsigned long long key =
        (((unsigned long long)__float_as_uint(v)) << 32) | (unsigned)(NN - 1 - cc);

    unsigned long long T = 0;
#pragma unroll 1
    for (int b = 63; b >= 32; --b) {
      const unsigned long long Tp = T | (1ULL << b);
      if (__popcll(__ballot(key >= Tp)) >= TOPK) T = Tp;
    }
#pragma unroll 1
    for (int b = 11; b >= 0; --b) {
      const unsigned long long Tp = T | (1ULL << b);
      if (__popcll(__ballot(key >= Tp)) >= TOPK) T = Tp;
    }

    const bool win = (key >= T);  // exactly 32 lanes
    float mx = v;
#pragma unroll
    for (int off = 32; off; off >>= 1) mx = fmaxf(mx, __shfl_xor(mx, off));
    const float e = win ? expf(v - mx) : 0.f;
    float sum = e;
#pragma unroll
    for (int off = 32; off; off >>= 1) sum += __shfl_xor(sum, off);

    const unsigned long long wm = __ballot(win);
    if (win) {
      const int slot = (int)__builtin_amdgcn_mbcnt_hi(
          (unsigned)(wm >> 32), __builtin_amdgcn_mbcnt_lo((unsigned)wm, 0));
      probs[(size_t)r * TOPK + slot] = e / sum;
      pidx [(size_t)r * TOPK + slot] = cc;
    }
  }
}

// ---------------------------------------------------------------------------
// K3: ff1 = relu(tgt1 @ w1^T + b1). A reg-staged from row-major bf16 t1b16,
// B via gload16 from w1pack. bf16 row-major out. grid 512.
// ---------------------------------------------------------------------------
__global__ __launch_bounds__(256) void k_ffgemm1_pk(
    const unsigned short* __restrict__ Ab16,
    const unsigned short* __restrict__ wpk,
    const float* __restrict__ bias,
    unsigned short* __restrict__ Cb) {
  __shared__ __align__(16) unsigned short Al[512 * 8];
  __shared__ __align__(16) unsigned short Bl[512 * 8];
  const int tid = threadIdx.x;
  const int lane = tid & 63, wid = tid >> 6;
  const int wr = wid >> 1, wc = wid & 1;
  const int bm = blockIdx.x >> 1, bn = blockIdx.x & 1;
  const int m0 = bm * 128, n0 = bn * 128;

  f32x4 acc[4][4];
#pragma unroll
  for (int i = 0; i < 4; ++i)
#pragma unroll
    for (int j = 0; j < 4; ++j) acc[i][j] = (f32x4){0.f, 0.f, 0.f, 0.f};

  unsigned short* lB0 = Bl + (size_t)(wid * 64) * 8;
  unsigned short* lB1 = Bl + (size_t)(256 + wid * 64) * 8;
  const int row0 = tid & 127, g0 = tid >> 7, g1 = g0 + 2;

  for (int t = 0; t < 8; ++t) {
    const unsigned short* gw = wpk + (size_t)(bn * 8 + t) * 4096;
    __syncthreads();
    const uint4 a0 = *reinterpret_cast<const uint4*>(
        Ab16 + (size_t)(m0 + row0) * HH + t * 32 + g0 * 8);
    const uint4 a1 = *reinterpret_cast<const uint4*>(
        Ab16 + (size_t)(m0 + row0) * HH + t * 32 + g1 * 8);
    *reinterpret_cast<uint4*>(Al + (size_t)tid * 8) = a0;
    *reinterpret_cast<uint4*>(Al + (size_t)(256 + tid) * 8) = a1;
    gload16(gw + (size_t)tid * 8, lB0);
    gload16(gw + (size_t)(256 + tid) * 8, lB1);
    __syncthreads();
    mfma_tile(Al, Bl, wr, wc, lane, acc);
  }

  const int crow = m0 + wr * 64 + (lane >> 4) * 4;
  const int ccol = n0 + wc * 64 + (lane & 15);
#pragma unroll
  for (int i = 0; i < 4; ++i)
#pragma unroll
    for (int j = 0; j < 4; ++j) {
      const float bv = bias[ccol + j * 16];
      unsigned short* cp = Cb + (size_t)(crow + i * 16) * HH + ccol + j * 16;
#pragma unroll
      for (int q = 0; q < 4; ++q)
        cp[(size_t)q * HH] = f2bf(fmaxf(acc[i][j][q] + bv, 0.f));
    }
}

// ---------------------------------------------------------------------------
// K4: ff2 = ff1 @ w2^T + b2. A reg-staged from row-major bf16, B gload16.
// ---------------------------------------------------------------------------
__global__ __launch_bounds__(256) void k_ffgemm2_pk(
    const unsigned short* __restrict__ Ab16,
    const unsigned short* __restrict__ wpk,
    const float* __restrict__ bias,
    float* __restrict__ C) {
  __shared__ __align__(16) unsigned short Al[512 * 8];
  __shared__ __align__(16) unsigned short Bl[512 * 8];
  const int tid = threadIdx.x;
  const int lane = tid & 63, wid = tid >> 6;
  const int wr = wid >> 1, wc = wid & 1;
  const int bm = blockIdx.x >> 1, bn = blockIdx.x & 1;
  const int m0 = bm * 128, n0 = bn * 128;

  f32x4 acc[4][4];
#pragma unroll
  for (int i = 0; i < 4; ++i)
#pragma unroll
    for (int j = 0; j < 4; ++j) acc[i][j] = (f32x4){0.f, 0.f, 0.f, 0.f};

  unsigned short* lB0 = Bl + (size_t)(wid * 64) * 8;
  unsigned short* lB1 = Bl + (size_t)(256 + wid * 64) * 8;
  const int row0 = tid & 127, g0 = tid >> 7, g1 = g0 + 2;

  for (int t = 0; t < 8; ++t) {
    const unsigned short* gw = wpk + (size_t)(bn * 8 + t) * 4096;
    __syncthreads();
    const uint4 a0 = *reinterpret_cast<const uint4*>(
        Ab16 + (size_t)(m0 + row0) * HH + t * 32 + g0 * 8);
    const uint4 a1 = *reinterpret_cast<const uint4*>(
        Ab16 + (size_t)(m0 + row0) * HH + t * 32 + g1 * 8);
    *reinterpret_cast<uint4*>(Al + (size_t)tid * 8) = a0;
    *reinterpret_cast<uint4*>(Al + (size_t)(256 + tid) * 8) = a1;
    gload16(gw + (size_t)tid * 8, lB0);
    gload16(gw + (size_t)(256 + tid) * 8, lB1);
    __syncthreads();
    mfma_tile(Al, Bl, wr, wc, lane, acc);
  }

  const int crow = m0 + wr * 64 + (lane >> 4) * 4;
  const int ccol = n0 + wc * 64 + (lane & 15);
#pragma unroll
  for (int i = 0; i < 4; ++i)
#pragma unroll
    for (int j = 0; j < 4; ++j) {
      const float bv = bias[ccol + j * 16];
      float* cp = C + (size_t)(crow + i * 16) * HH + ccol + j * 16;
#pragma unroll
      for (int q = 0; q < 4; ++q) cp[(size_t)q * HH] = acc[i][j][q] + bv;
    }
}

// ---------------------------------------------------------------------------
// K2: gc gather (bf16 src) + residual + LN1 -> t1b16 (bf16 row-major).
// Single-batch blocks, grid (512, 8) x-major. NOTE: plain launch_bounds(256)
// — R18's (256,8) cap raised occupancy 17->81% but the co-resident blocks
// then spanned multiple batch slabs, blowing the 4MB per-XCD L2 working set
// (FETCH 27.7 -> 361 MB, 38.8 -> 299 us). Low occupancy here is protective:
// it keeps one 2.1MB slab L2-resident. Do NOT re-add a min-waves bound.
// ---------------------------------------------------------------------------
__global__ __launch_bounds__(256) void k_gather_ln1(
    const unsigned short* __restrict__ s16, const float* __restrict__ tgt,
    const float* __restrict__ probs, const int* __restrict__ pidx,
    const float* __restrict__ lnw, const float* __restrict__ lnb,
    unsigned short* __restrict__ t1b16) {
  __shared__ float lp[8][TOPK];
  __shared__ int li[8][TOPK];
  const int mt = blockIdx.x, b = blockIdx.y;
  const int tid = threadIdx.x;
  const int mloc = tid >> 5, kg = tid & 31, h8 = kg * 8;
  const int m = mt * 8 + mloc;
  lp[mloc][kg] = probs[(size_t)m * TOPK + kg];
  li[mloc][kg] = pidx[(size_t)m * TOPK + kg];
  __syncthreads();

  const unsigned short* sb = s16 + (size_t)b * NN * HH + h8;

  float acc[8] = {0.f, 0.f, 0.f, 0.f, 0.f, 0.f, 0.f, 0.f};
#pragma unroll
  for (int k = 0; k < TOPK; ++k) {
    const bf16x8 v = *reinterpret_cast<const bf16x8*>(sb + (size_t)li[mloc][k] * HH);
    const float p = lp[mloc][k];
#pragma unroll
    for (int e = 0; e < 8; ++e)
      acc[e] = fmaf(p, bf2f((unsigned short)v[e]), acc[e]);
  }

  const size_t obase = ((size_t)b * NN + m) * HH + h8;
  const float4 t0 = *reinterpret_cast<const float4*>(tgt + obase);
  const float4 t1 = *reinterpret_cast<const float4*>(tgt + obase + 4);
  acc[0] += t0.x; acc[1] += t0.y; acc[2] += t0.z; acc[3] += t0.w;
  acc[4] += t1.x; acc[5] += t1.y; acc[6] += t1.z; acc[7] += t1.w;

  float s = 0.f, s2 = 0.f;
#pragma unroll
  for (int e = 0; e < 8; ++e) { s += acc[e]; s2 = fmaf(acc[e], acc[e], s2); }
#pragma unroll
  for (int off = 16; off; off >>= 1) {
    s += __shfl_xor(s, off, 32);
    s2 += __shfl_xor(s2, off, 32);
  }
  const float mu = s * (1.f / HH);
  const float var = s2 * (1.f / HH) - mu * mu;
  const float rs = rsqrtf(var + LN_EPS);

  const float4 w0 = *reinterpret_cast<const float4*>(lnw + h8);
  const float4 w1 = *reinterpret_cast<const float4*>(lnw + h8 + 4);
  const float4 c0 = *reinterpret_cast<const float4*>(lnb + h8);
  const float4 c1 = *reinterpret_cast<const float4*>(lnb + h8 + 4);
  const float wv[8] = {w0.x, w0.y, w0.z, w0.w, w1.x, w1.y, w1.z, w1.w};
  const float cv[8] = {c0.x, c0.y, c0.z, c0.w, c1.x, c1.y, c1.z, c1.w};
  union { unsigned short us[8]; uint4 q; } ot;
#pragma unroll
  for (int e = 0; e < 8; ++e)
    ot.us[e] = f2bf((acc[e] - mu) * rs * wv[e] + cv[e]);
  *reinterpret_cast<uint4*>(t1b16 + obase) = ot.q;
}

// ---------------------------------------------------------------------------
// K5: out = LN2(t1b16 + ff2) -> d_out (fp32). 8 rows/block, 32 lanes/row.
// ---------------------------------------------------------------------------
__global__ __launch_bounds__(256) void k_res_ln2(
    const unsigned short* __restrict__ t1b16, const float* __restrict__ ff,
    const float* __restrict__ lnw, const float* __restrict__ lnb,
    float* __restrict__ out) {
  const int tid = threadIdx.x;
  const int rloc = tid >> 5, kg = tid & 31, h8 = kg * 8;
  const size_t row = (size_t)blockIdx.x * 8 + rloc;
  const size_t obase = row * HH + h8;

  const bf16x8 t = *reinterpret_cast<const bf16x8*>(t1b16 + obase);
  const float4 f0 = *reinterpret_cast<const float4*>(ff + obase);
  const float4 f1 = *reinterpret_cast<const float4*>(ff + obase + 4);
  float x[8];
  x[0] = bf2f((unsigned short)t[0]) + f0.x;
  x[1] = bf2f((unsigned short)t[1]) + f0.y;
  x[2] = bf2f((unsigned short)t[2]) + f0.z;
  x[3] = bf2f((unsigned short)t[3]) + f0.w;
  x[4] = bf2f((unsigned short)t[4]) + f1.x;
  x[5] = bf2f((unsigned short)t[5]) + f1.y;
  x[6] = bf2f((unsigned short)t[6]) + f1.z;
  x[7] = bf2f((unsigned short)t[7]) + f1.w;

  float s = 0.f, s2 = 0.f;
#pragma unroll
  for (int e = 0; e < 8; ++e) { s += x[e]; s2 = fmaf(x[e], x[e], s2); }
#pragma unroll
  for (int off = 16; off; off >>= 1) {
    s += __shfl_xor(s, off, 32);
    s2 += __shfl_xor(s2, off, 32);
  }
  const float mu = s * (1.f / HH);
  const float var = s2 * (1.f / HH) - mu * mu;
  const float rs = rsqrtf(var + LN_EPS);

  const float4 w0 = *reinterpret_cast<const float4*>(lnw + h8);
  const float4 w1 = *reinterpret_cast<const float4*>(lnw + h8 + 4);
  const float4 c0 = *reinterpret_cast<const float4*>(lnb + h8);
  const float4 c1 = *reinterpret_cast<const float4*>(lnb + h8 + 4);
  float4 o0, o1;
  o0.x = (x[0] - mu) * rs * w0.x + c0.x;
  o0.y = (x[1] - mu) * rs * w0.y + c0.y;
  o0.z = (x[2] - mu) * rs * w0.z + c0.z;
  o0.w = (x[3] - mu) * rs * w0.w + c0.w;
  o1.x = (x[4] - mu) * rs * w1.x + c1.x;
  o1.y = (x[5] - mu) * rs * w1.y + c1.y;
  o1.z = (x[6] - mu) * rs * w1.z + c1.z;
  o1.w = (x[7] - mu) * rs * w1.w + c1.w;
  *reinterpret_cast<float4*>(out + obase) = o0;
  *reinterpret_cast<float4*>(out + obase + 4) = o1;
}

// ---------------------------------------------------------------------------
extern "C" void kernel_launch(void* const* d_in, const int* in_sizes, int n_in,
                              void* d_out, int out_size, void* d_ws, size_t ws_size,
                              hipStream_t stream) {
  const float* src  = (const float*)d_in[0];
  const float* tgt  = (const float*)d_in[1];
  const float* n1   = (const float*)d_in[2];
  const float* n2   = (const float*)d_in[3];
  const float* w1   = (const float*)d_in[4];
  const float* b1   = (const float*)d_in[5];
  const float* w2   = (const float*)d_in[6];
  const float* b2   = (const float*)d_in[7];
  const float* ln1w = (const float*)d_in[8];
  const float* ln1b = (const float*)d_in[9];
  const float* ln2w = (const float*)d_in[10];
  const float* ln2b = (const float*)d_in[11];
  float* out = (float*)d_out;

  // ws: probs(512K) | pidx(512K) | 64MiB region | apack 2M | bpack 2M
  //     | wpacks 256K @68M | cand 1M @69M
  // region lifetime interval map (byte offsets; audited):
  //   adjb   [0,32M)   adjgemm -> topk64 (bf16; dead before srcpack)
  //   s16    [0,16M)   srcpack -> gather (dead before ffgemm2)
  //   ff1b16 [32,48M)  ffgemm1 -> ffgemm2
  //   t1b16  [48,64M)  gather -> ffgemm1 + res_ln2
  //   ff2    [0,32M)   ffgemm2 -> res_ln2 (overlaps only dead s16/adjb)
  //   cand @69M: topk64 -> refine (outside the 64M region; no conflicts)
  float* wsf   = (float*)d_ws;
  float* probs = wsf;
  int*   pidx  = (int*)(wsf + (size_t)NN * TOPK);
  char*  cbase = (char*)(wsf + 2 * (size_t)NN * TOPK);
  unsigned short* adjb   = (unsigned short*)cbase;
  unsigned short* s16    = (unsigned short*)cbase;
  unsigned short* ff1b16 = (unsigned short*)(cbase + ((size_t)32 << 20));
  unsigned short* t1b16  = (unsigned short*)(cbase + ((size_t)48 << 20));
  float* ff2   = (float*)cbase;
  unsigned short* apack  = (unsigned short*)(cbase + ((size_t)64 << 20));
  unsigned short* bpack  = (unsigned short*)(cbase + ((size_t)66 << 20));
  unsigned short* w1pack = (unsigned short*)(cbase + ((size_t)68 << 20));
  unsigned short* w2pack = w1pack + 65536;
  int* cand = (int*)(cbase + ((size_t)69 << 20));

  dim3 gp(512, 2);
  k_pack<<<gp, 256, 0, stream>>>(n1, n2, apack, bpack);
  k_adjgemm_pk<<<(NN / 128) * (NN / 128), 256, 0, stream>>>(apack, bpack, adjb);
  k_topk64<<<NN / 4, 256, 0, stream>>>(adjb, cand);
  k_refine<<<NN, 256, 0, stream>>>(n1, n2, cand, probs, pidx);

  k_srcpack<<<(BATCH * NN * HH) / (256 * 8), 256, 0, stream>>>(src, s16);
  dim3 gw(32, 2);
  k_packw<<<gw, 256, 0, stream>>>(w1, w2, w1pack, w2pack);

  dim3 gg(NN / 8, BATCH);  // single-batch blocks, x-major (L2 slab residency)
  k_gather_ln1<<<gg, 256, 0, stream>>>(s16, tgt, probs, pidx, ln1w, ln1b, t1b16);

  const int gemm_grid = (BATCH * NN / 128) * (HH / 128);  // 512
  k_ffgemm1_pk<<<gemm_grid, 256, 0, stream>>>(t1b16, w1pack, b1, ff1b16);
  k_ffgemm2_pk<<<gemm_grid, 256, 0, stream>>>(ff1b16, w2pack, b2, ff2);

  k_res_ln2<<<BATCH * NN / 8, 256, 0, stream>>>(t1b16, ff2, ln2w, ln2b, out);
}

// Round 20
// 156.086 us; speedup vs baseline: 2.7499x; 1.0122x over previous
//
#include <hip/hip_runtime.h>
#include <math.h>

#define NN 4096
#define HH 256
#define BATCH 8
#define TOPK 32
#define NSEL 64
#define LN_EPS 1e-5f

typedef float f32x4 __attribute__((ext_vector_type(4)));
typedef short bf16x8 __attribute__((ext_vector_type(8)));

__device__ __forceinline__ unsigned short f2bf(float x) {
  unsigned u = __float_as_uint(x);
  u += 0x7FFF + ((u >> 16) & 1);  // RNE
  return (unsigned short)(u >> 16);
}
__device__ __forceinline__ float bf2f(unsigned short h) {
  return __uint_as_float(((unsigned)h) << 16);
}

// async global->LDS, 16B per lane; LDS dest is wave-uniform base + lane*16
__device__ __forceinline__ void gload16(const void* g, void* l) {
  __builtin_amdgcn_global_load_lds(
      (const __attribute__((address_space(1))) void*)g,
      (__attribute__((address_space(3))) void*)l, 16, 0, 0);
}

// one BK=32 K-step: 4x4 fragment MFMAs from [g:4][row:128][8] LDS tiles
__device__ __forceinline__ void mfma_tile(const unsigned short* Al,
                                          const unsigned short* Bl,
                                          int wr, int wc, int lane,
                                          f32x4 acc[4][4]) {
  const int g = lane >> 4, r = lane & 15;
  bf16x8 a[4], b[4];
#pragma unroll
  for (int i = 0; i < 4; ++i)
    a[i] = *reinterpret_cast<const bf16x8*>(Al + ((size_t)(g * 128 + wr * 64 + i * 16 + r)) * 8);
#pragma unroll
  for (int j = 0; j < 4; ++j)
    b[j] = *reinterpret_cast<const bf16x8*>(Bl + ((size_t)(g * 128 + wc * 64 + j * 16 + r)) * 8);
#pragma unroll
  for (int i = 0; i < 4; ++i)
#pragma unroll
    for (int j = 0; j < 4; ++j)
      acc[i][j] = __builtin_amdgcn_mfma_f32_16x16x32_bf16(a[i], b[j], acc[i][j], 0, 0, 0);
}

// ---------------------------------------------------------------------------
// K0: bf16 (hi-only) pack of n1/n2 into GEMM LDS slot order. 8 K-steps.
// ---------------------------------------------------------------------------
__global__ __launch_bounds__(256) void k_pack(
    const float* __restrict__ n1, const float* __restrict__ n2,
    unsigned short* __restrict__ apack, unsigned short* __restrict__ bpack) {
  const int u = blockIdx.x * 256 + threadIdx.x;  // 0..131071
  const float* srcm = blockIdx.y ? n2 : n1;
  unsigned short* dstm = blockIdx.y ? bpack : apack;
  const int row = u >> 5, kg = u & 31;
  const int st = kg >> 2, g = kg & 3;
  const int bm = row >> 7, slot = g * 128 + (row & 127);

  const float4 v0 = *reinterpret_cast<const float4*>(srcm + (size_t)row * HH + kg * 8);
  const float4 v1 = *reinterpret_cast<const float4*>(srcm + (size_t)row * HH + kg * 8 + 4);
  const float xs[8] = {v0.x, v0.y, v0.z, v0.w, v1.x, v1.y, v1.z, v1.w};
  union { unsigned short s[8]; uint4 q; } hi;
#pragma unroll
  for (int e = 0; e < 8; ++e) hi.s[e] = f2bf(xs[e]);
  *reinterpret_cast<uint4*>(dstm + ((size_t)(bm * 8 + st) * 512 + slot) * 8) = hi.q;
}

// ---------------------------------------------------------------------------
// K0b: src fp32 -> bf16 (blocks 0..4095) + w1/w2 slot-order packs (blocks
// 4096..4159, 64 blocks = 16384 threads). Runs AFTER k_topk64.
// ---------------------------------------------------------------------------
__global__ __launch_bounds__(256) void k_srcpack(
    const float* __restrict__ src, unsigned short* __restrict__ s16,
    const float* __restrict__ w1, const float* __restrict__ w2,
    unsigned short* __restrict__ w1pack, unsigned short* __restrict__ w2pack) {
  if (blockIdx.x < 4096) {
    const size_t i = ((size_t)blockIdx.x * 256 + threadIdx.x) * 8;
    const float4 v0 = *reinterpret_cast<const float4*>(src + i);
    const float4 v1 = *reinterpret_cast<const float4*>(src + i + 4);
    const float xs[8] = {v0.x, v0.y, v0.z, v0.w, v1.x, v1.y, v1.z, v1.w};
    union { unsigned short s[8]; uint4 q; } p;
#pragma unroll
    for (int e = 0; e < 8; ++e) p.s[e] = f2bf(xs[e]);
    *reinterpret_cast<uint4*>(s16 + i) = p.q;
  } else {
    const int idx = (blockIdx.x - 4096) * 256 + threadIdx.x;  // 0..16383
    const int mat = idx >> 13, u = idx & 8191;
    const float* srcm = mat ? w2 : w1;
    unsigned short* dstm = mat ? w2pack : w1pack;
    const int row = u >> 5, kg = u & 31;
    const int st = kg >> 2, g = kg & 3;
    const int bn = row >> 7, slot = g * 128 + (row & 127);
    const float4 v0 = *reinterpret_cast<const float4*>(srcm + (size_t)row * HH + kg * 8);
    const float4 v1 = *reinterpret_cast<const float4*>(srcm + (size_t)row * HH + kg * 8 + 4);
    const float xs[8] = {v0.x, v0.y, v0.z, v0.w, v1.x, v1.y, v1.z, v1.w};
    union { unsigned short s[8]; uint4 q; } p;
#pragma unroll
    for (int e = 0; e < 8; ++e) p.s[e] = f2bf(xs[e]);
    *reinterpret_cast<uint4*>(dstm + ((size_t)(bn * 8 + st) * 512 + slot) * 8) = p.q;
  }
}

// ---------------------------------------------------------------------------
// K1a: adjb ~= bf16(n1 @ n2^T), ONE bf16 phase. Selection-only values:
// storage rounding (+-0.125) + GEMM bf16 error both << v32-v64 gap (~0.93);
// exact values recomputed by k_refine. 8 K-steps, XCD-swizzled. grid 1024.
// ---------------------------------------------------------------------------
__global__ __launch_bounds__(256) void k_adjgemm_pk(
    const unsigned short* __restrict__ apack,
    const unsigned short* __restrict__ bpack,
    unsigned short* __restrict__ adjb) {
  __shared__ __align__(16) unsigned short Al[512 * 8];
  __shared__ __align__(16) unsigned short Bl[512 * 8];
  const int tid = threadIdx.x;
  const int lane = tid & 63, wid = tid >> 6;
  const int wr = wid >> 1, wc = wid & 1;
  const int wgid = (blockIdx.x & 7) * 128 + (blockIdx.x >> 3);  // XCD swizzle
  const int bm = wgid >> 5, bn = wgid & 31;
  const int m0 = bm * 128, n0 = bn * 128;

  f32x4 acc[4][4];
#pragma unroll
  for (int i = 0; i < 4; ++i)
#pragma unroll
    for (int j = 0; j < 4; ++j) acc[i][j] = (f32x4){0.f, 0.f, 0.f, 0.f};

  unsigned short* lA0 = Al + (size_t)(wid * 64) * 8;
  unsigned short* lA1 = Al + (size_t)(256 + wid * 64) * 8;
  unsigned short* lB0 = Bl + (size_t)(wid * 64) * 8;
  unsigned short* lB1 = Bl + (size_t)(256 + wid * 64) * 8;

  for (int t = 0; t < 8; ++t) {
    const unsigned short* ga = apack + (size_t)(bm * 8 + t) * 4096;
    const unsigned short* gb = bpack + (size_t)(bn * 8 + t) * 4096;
    __syncthreads();
    gload16(ga + (size_t)tid * 8, lA0);
    gload16(ga + (size_t)(256 + tid) * 8, lA1);
    gload16(gb + (size_t)tid * 8, lB0);
    gload16(gb + (size_t)(256 + tid) * 8, lB1);
    __syncthreads();
    mfma_tile(Al, Bl, wr, wc, lane, acc);
  }

  const int crow = m0 + wr * 64 + (lane >> 4) * 4;
  const int ccol = n0 + wc * 64 + (lane & 15);
#pragma unroll
  for (int i = 0; i < 4; ++i)
#pragma unroll
    for (int j = 0; j < 4; ++j) {
      unsigned short* cp = adjb + (size_t)(crow + i * 16) * NN + ccol + j * 16;
#pragma unroll
      for (int q = 0; q < 4; ++q) cp[(size_t)q * NN] = f2bf(acc[i][j][q]);
    }
}

// ---------------------------------------------------------------------------
// K1b: per-row approx top-64 candidate indices via ballot-bisection, from
// the bf16 adj (half the scan traffic). Keys unique via idx field.
// ---------------------------------------------------------------------------
__global__ __launch_bounds__(256) void k_topk64(
    const unsigned short* __restrict__ adjb, int* __restrict__ cand) {
  const int tid = threadIdx.x;
  const int wid = tid >> 6, lane = tid & 63;
  const int r = blockIdx.x * 4 + wid;
  const bf16x8* rp8 = reinterpret_cast<const bf16x8*>(adjb + (size_t)r * NN);

#define KEY(v, ix) ((((unsigned long long)__float_as_uint(v)) << 32) | \
                    (unsigned)(NN - 1 - (ix)))

  unsigned long long k1 = 0, k2 = 0, k3 = 0, k4 = 0;
  unsigned long long k5 = 0, k6 = 0, k7 = 0, k8 = 0;

#define INS4(kk)                                              \
  do { const unsigned long long _k = (kk);                    \
    if (_k > k4) {                                            \
      if (_k > k1)      { k4 = k3; k3 = k2; k2 = k1; k1 = _k; } \
      else if (_k > k2) { k4 = k3; k3 = k2; k2 = _k; }        \
      else if (_k > k3) { k4 = k3; k3 = _k; }                 \
      else              { k4 = _k; } } } while (0)
#define INS8(kk)                                              \
  do { const unsigned long long _k = (kk);                    \
    if (_k > k8) {                                            \
      if (_k > k5)      { k8 = k7; k7 = k6; k6 = k5; k5 = _k; } \
      else if (_k > k6) { k8 = k7; k7 = k6; k6 = _k; }        \
      else if (_k > k7) { k8 = k7; k7 = _k; }                 \
      else              { k8 = _k; } } } while (0)

#pragma unroll
  for (int j = 0; j < 8; ++j) {
    const bf16x8 v = rp8[j * 64 + lane];
    const int ib = (j * 64 + lane) * 8;
#pragma unroll
    for (int e = 0; e < 8; ++e)
      INS4(KEY(bf2f((unsigned short)v[e]), ib + e));
  }

  auto bisect = [&]() -> unsigned long long {
    unsigned long long T = 0;
#pragma unroll 1
    for (int b = 63; b >= 32; --b) {
      const unsigned long long Tp = T | (1ULL << b);
      const int cnt = __popcll(__ballot(k1 >= Tp)) + __popcll(__ballot(k2 >= Tp)) +
                      __popcll(__ballot(k3 >= Tp)) + __popcll(__ballot(k4 >= Tp)) +
                      __popcll(__ballot(k5 >= Tp)) + __popcll(__ballot(k6 >= Tp)) +
                      __popcll(__ballot(k7 >= Tp)) + __popcll(__ballot(k8 >= Tp));
      if (cnt >= NSEL) T = Tp;
    }
#pragma unroll 1
    for (int b = 11; b >= 0; --b) {
      const unsigned long long Tp = T | (1ULL << b);
      const int cnt = __popcll(__ballot(k1 >= Tp)) + __popcll(__ballot(k2 >= Tp)) +
                      __popcll(__ballot(k3 >= Tp)) + __popcll(__ballot(k4 >= Tp)) +
                      __popcll(__ballot(k5 >= Tp)) + __popcll(__ballot(k6 >= Tp)) +
                      __popcll(__ballot(k7 >= Tp)) + __popcll(__ballot(k8 >= Tp));
      if (cnt >= NSEL) T = Tp;
    }
    return T;
  };

  unsigned long long T = bisect();

  if (__any(k4 >= T)) {
    if (k4 >= T) {  // suspect lanes build their next-4 (keys < k4)
      const unsigned long long kmin = k4;
#pragma unroll 1
      for (int j = 0; j < 8; ++j) {
        const bf16x8 v = rp8[j * 64 + lane];
        const int ib = (j * 64 + lane) * 8;
#pragma unroll
        for (int e = 0; e < 8; ++e) {
          const unsigned long long kk = KEY(bf2f((unsigned short)v[e]), ib + e);
          if (kk < kmin) INS8(kk);
        }
      }
    }
    T = bisect();
    if (__any(k8 >= T)) {
      // exact serial fallback (rare): 64 ordered extractions
      unsigned long long W = ~0ULL;
      int outi = 0;
#pragma unroll 1
      for (int it = 0; it < NSEL; ++it) {
        unsigned long long best = 0;
        for (int j = 0; j < 8; ++j) {
          const bf16x8 v = rp8[j * 64 + lane];
          const int ib = (j * 64 + lane) * 8;
#pragma unroll
          for (int e = 0; e < 8; ++e) {
            const unsigned long long kk = KEY(bf2f((unsigned short)v[e]), ib + e);
            if (kk < W && kk > best) best = kk;
          }
        }
#pragma unroll
        for (int off = 32; off; off >>= 1) {
          const unsigned long long o = __shfl_xor(best, off);
          if (o > best) best = o;
        }
        if (lane == it) outi = NN - 1 - (int)(best & 0xFFFFFFFFu);
        W = best;
      }
      cand[(size_t)r * NSEL + lane] = outi;
      return;
    }
  }

  // emission: keys >= T (exactly 64), arbitrary order
  const unsigned long long m1 = __ballot(k1 >= T), m2 = __ballot(k2 >= T);
  const unsigned long long m3 = __ballot(k3 >= T), m4 = __ballot(k4 >= T);
  const unsigned long long m5 = __ballot(k5 >= T), m6 = __ballot(k6 >= T);
  const unsigned long long m7 = __ballot(k7 >= T), m8 = __ballot(k8 >= T);

  auto mb = [](unsigned long long m) -> int {
    return (int)__builtin_amdgcn_mbcnt_hi(
        (unsigned)(m >> 32), __builtin_amdgcn_mbcnt_lo((unsigned)m, 0));
  };
  const int c1 = __popcll(m1), c2 = __popcll(m2), c3 = __popcll(m3);
  const int c4 = __popcll(m4), c5 = __popcll(m5), c6 = __popcll(m6);
  const int c7 = __popcll(m7);
  const int b2 = c1, b3 = b2 + c2, b4 = b3 + c3, b5 = b4 + c4;
  const int b6 = b5 + c5, b7 = b6 + c6, b8 = b7 + c7;

  int* cp = cand + (size_t)r * NSEL;
  if (k1 >= T) cp[     mb(m1)] = NN - 1 - (int)(k1 & 0xFFFFFFFFu);
  if (k2 >= T) cp[b2 + mb(m2)] = NN - 1 - (int)(k2 & 0xFFFFFFFFu);
  if (k3 >= T) cp[b3 + mb(m3)] = NN - 1 - (int)(k3 & 0xFFFFFFFFu);
  if (k4 >= T) cp[b4 + mb(m4)] = NN - 1 - (int)(k4 & 0xFFFFFFFFu);
  if (k5 >= T) cp[b5 + mb(m5)] = NN - 1 - (int)(k5 & 0xFFFFFFFFu);
  if (k6 >= T) cp[b6 + mb(m6)] = NN - 1 - (int)(k6 & 0xFFFFFFFFu);
  if (k7 >= T) cp[b7 + mb(m7)] = NN - 1 - (int)(k7 & 0xFFFFFFFFu);
  if (k8 >= T) cp[b8 + mb(m8)] = NN - 1 - (int)(k8 & 0xFFFFFFFFu);
#undef INS4
#undef INS8
#undef KEY
}

// ---------------------------------------------------------------------------
// K1c: exact refine, coalesced (interleaved segments). One block per row;
// 4 lanes/candidate, lane s reads float4 idx j*4+s -> 64B contiguous per
// candidate per instruction. Wave 0: exact top-32-of-64 + softmax + emit.
// ---------------------------------------------------------------------------
__global__ __launch_bounds__(256) void k_refine(
    const float* __restrict__ n1, const float* __restrict__ n2,
    const int* __restrict__ cand,
    float* __restrict__ probs, int* __restrict__ pidx) {
  __shared__ float a_sh[HH];
  __shared__ float cv[NSEL];
  __shared__ int ci[NSEL];
  const int r = blockIdx.x;
  const int tid = threadIdx.x;

  a_sh[tid] = n1[(size_t)r * HH + tid];
  const int c = cand[(size_t)r * NSEL + (tid >> 2)];
  __syncthreads();

  const int s = tid & 3;  // interleave: float4 index j*4+s
  const float4* br = reinterpret_cast<const float4*>(n2 + (size_t)c * HH);
  const float4* ar = reinterpret_cast<const float4*>(a_sh);
  float a0 = 0.f, a1 = 0.f, a2 = 0.f, a3 = 0.f;
#pragma unroll
  for (int j = 0; j < 16; j += 4) {
    const float4 bx = br[(j + 0) * 4 + s];
    const float4 by = br[(j + 1) * 4 + s];
    const float4 bz = br[(j + 2) * 4 + s];
    const float4 bw = br[(j + 3) * 4 + s];
    const float4 ax = ar[(j + 0) * 4 + s];
    const float4 ay = ar[(j + 1) * 4 + s];
    const float4 az = ar[(j + 2) * 4 + s];
    const float4 aw = ar[(j + 3) * 4 + s];
    a0 = fmaf(ax.x, bx.x, fmaf(ax.y, bx.y, fmaf(ax.z, bx.z, fmaf(ax.w, bx.w, a0))));
    a1 = fmaf(ay.x, by.x, fmaf(ay.y, by.y, fmaf(ay.z, by.z, fmaf(ay.w, by.w, a1))));
    a2 = fmaf(az.x, bz.x, fmaf(az.y, bz.y, fmaf(az.z, bz.z, fmaf(az.w, bz.w, a2))));
    a3 = fmaf(aw.x, bw.x, fmaf(aw.y, bw.y, fmaf(aw.z, bw.z, fmaf(aw.w, bw.w, a3))));
  }
  float acc = (a0 + a1) + (a2 + a3);
  acc += __shfl_xor(acc, 1);
  acc += __shfl_xor(acc, 2);
  if ((tid & 3) == 0) { cv[tid >> 2] = acc; ci[tid >> 2] = c; }
  __syncthreads();

  if (tid < NSEL) {  // wave 0: lane = candidate
    const float v = cv[tid];
    const int cc = ci[tid];
    const unsigned long long key =
        (((unsigned long long)__float_as_uint(v)) << 32) | (unsigned)(NN - 1 - cc);

    unsigned long long T = 0;
#pragma unroll 1
    for (int b = 63; b >= 32; --b) {
      const unsigned long long Tp = T | (1ULL << b);
      if (__popcll(__ballot(key >= Tp)) >= TOPK) T = Tp;
    }
#pragma unroll 1
    for (int b = 11; b >= 0; --b) {
      const unsigned long long Tp = T | (1ULL << b);
      if (__popcll(__ballot(key >= Tp)) >= TOPK) T = Tp;
    }

    const bool win = (key >= T);  // exactly 32 lanes
    float mx = v;
#pragma unroll
    for (int off = 32; off; off >>= 1) mx = fmaxf(mx, __shfl_xor(mx, off));
    const float e = win ? expf(v - mx) : 0.f;
    float sum = e;
#pragma unroll
    for (int off = 32; off; off >>= 1) sum += __shfl_xor(sum, off);

    const unsigned long long wm = __ballot(win);
    if (win) {
      const int slot = (int)__builtin_amdgcn_mbcnt_hi(
          (unsigned)(wm >> 32), __builtin_amdgcn_mbcnt_lo((unsigned)wm, 0));
      probs[(size_t)r * TOPK + slot] = e / sum;
      pidx [(size_t)r * TOPK + slot] = cc;
    }
  }
}

// ---------------------------------------------------------------------------
// K3: ff1 = relu(tgt1 @ w1^T + b1). A reg-staged from row-major bf16 t1b16,
// B via gload16 from w1pack. bf16 row-major out. grid 512.
// ---------------------------------------------------------------------------
__global__ __launch_bounds__(256) void k_ffgemm1_pk(
    const unsigned short* __restrict__ Ab16,
    const unsigned short* __restrict__ wpk,
    const float* __restrict__ bias,
    unsigned short* __restrict__ Cb) {
  __shared__ __align__(16) unsigned short Al[512 * 8];
  __shared__ __align__(16) unsigned short Bl[512 * 8];
  const int tid = threadIdx.x;
  const int lane = tid & 63, wid = tid >> 6;
  const int wr = wid >> 1, wc = wid & 1;
  const int bm = blockIdx.x >> 1, bn = blockIdx.x & 1;
  const int m0 = bm * 128, n0 = bn * 128;

  f32x4 acc[4][4];
#pragma unroll
  for (int i = 0; i < 4; ++i)
#pragma unroll
    for (int j = 0; j < 4; ++j) acc[i][j] = (f32x4){0.f, 0.f, 0.f, 0.f};

  unsigned short* lB0 = Bl + (size_t)(wid * 64) * 8;
  unsigned short* lB1 = Bl + (size_t)(256 + wid * 64) * 8;
  const int row0 = tid & 127, g0 = tid >> 7, g1 = g0 + 2;

  for (int t = 0; t < 8; ++t) {
    const unsigned short* gw = wpk + (size_t)(bn * 8 + t) * 4096;
    __syncthreads();
    const uint4 a0 = *reinterpret_cast<const uint4*>(
        Ab16 + (size_t)(m0 + row0) * HH + t * 32 + g0 * 8);
    const uint4 a1 = *reinterpret_cast<const uint4*>(
        Ab16 + (size_t)(m0 + row0) * HH + t * 32 + g1 * 8);
    *reinterpret_cast<uint4*>(Al + (size_t)tid * 8) = a0;
    *reinterpret_cast<uint4*>(Al + (size_t)(256 + tid) * 8) = a1;
    gload16(gw + (size_t)tid * 8, lB0);
    gload16(gw + (size_t)(256 + tid) * 8, lB1);
    __syncthreads();
    mfma_tile(Al, Bl, wr, wc, lane, acc);
  }

  const int crow = m0 + wr * 64 + (lane >> 4) * 4;
  const int ccol = n0 + wc * 64 + (lane & 15);
#pragma unroll
  for (int i = 0; i < 4; ++i)
#pragma unroll
    for (int j = 0; j < 4; ++j) {
      const float bv = bias[ccol + j * 16];
      unsigned short* cp = Cb + (size_t)(crow + i * 16) * HH + ccol + j * 16;
#pragma unroll
      for (int q = 0; q < 4; ++q)
        cp[(size_t)q * HH] = f2bf(fmaxf(acc[i][j][q] + bv, 0.f));
    }
}

// ---------------------------------------------------------------------------
// K4: ff2 = ff1 @ w2^T + b2, bf16 out (residual consumer tolerates bf16;
// halves write + res_ln2 read traffic). A reg-staged, B gload16.
// ---------------------------------------------------------------------------
__global__ __launch_bounds__(256) void k_ffgemm2_pk(
    const unsigned short* __restrict__ Ab16,
    const unsigned short* __restrict__ wpk,
    const float* __restrict__ bias,
    unsigned short* __restrict__ Cb) {
  __shared__ __align__(16) unsigned short Al[512 * 8];
  __shared__ __align__(16) unsigned short Bl[512 * 8];
  const int tid = threadIdx.x;
  const int lane = tid & 63, wid = tid >> 6;
  const int wr = wid >> 1, wc = wid & 1;
  const int bm = blockIdx.x >> 1, bn = blockIdx.x & 1;
  const int m0 = bm * 128, n0 = bn * 128;

  f32x4 acc[4][4];
#pragma unroll
  for (int i = 0; i < 4; ++i)
#pragma unroll
    for (int j = 0; j < 4; ++j) acc[i][j] = (f32x4){0.f, 0.f, 0.f, 0.f};

  unsigned short* lB0 = Bl + (size_t)(wid * 64) * 8;
  unsigned short* lB1 = Bl + (size_t)(256 + wid * 64) * 8;
  const int row0 = tid & 127, g0 = tid >> 7, g1 = g0 + 2;

  for (int t = 0; t < 8; ++t) {
    const unsigned short* gw = wpk + (size_t)(bn * 8 + t) * 4096;
    __syncthreads();
    const uint4 a0 = *reinterpret_cast<const uint4*>(
        Ab16 + (size_t)(m0 + row0) * HH + t * 32 + g0 * 8);
    const uint4 a1 = *reinterpret_cast<const uint4*>(
        Ab16 + (size_t)(m0 + row0) * HH + t * 32 + g1 * 8);
    *reinterpret_cast<uint4*>(Al + (size_t)tid * 8) = a0;
    *reinterpret_cast<uint4*>(Al + (size_t)(256 + tid) * 8) = a1;
    gload16(gw + (size_t)tid * 8, lB0);
    gload16(gw + (size_t)(256 + tid) * 8, lB1);
    __syncthreads();
    mfma_tile(Al, Bl, wr, wc, lane, acc);
  }

  const int crow = m0 + wr * 64 + (lane >> 4) * 4;
  const int ccol = n0 + wc * 64 + (lane & 15);
#pragma unroll
  for (int i = 0; i < 4; ++i)
#pragma unroll
    for (int j = 0; j < 4; ++j) {
      const float bv = bias[ccol + j * 16];
      unsigned short* cp = Cb + (size_t)(crow + i * 16) * HH + ccol + j * 16;
#pragma unroll
      for (int q = 0; q < 4; ++q) cp[(size_t)q * HH] = f2bf(acc[i][j][q] + bv);
    }
}

// ---------------------------------------------------------------------------
// K2: gc gather (bf16 src) + residual + LN1 -> t1b16 (bf16 row-major).
// Single-batch blocks, grid (512, 8) x-major. NOTE: plain launch_bounds(256)
// — R18's (256,8) cap raised occupancy 17->81% but the co-resident blocks
// then spanned multiple batch slabs, blowing the 4MB per-XCD L2 working set
// (FETCH 27.7 -> 361 MB, 38.8 -> 299 us). Low occupancy here is protective:
// it keeps one 2.1MB slab L2-resident. Do NOT re-add a min-waves bound.
// ---------------------------------------------------------------------------
__global__ __launch_bounds__(256) void k_gather_ln1(
    const unsigned short* __restrict__ s16, const float* __restrict__ tgt,
    const float* __restrict__ probs, const int* __restrict__ pidx,
    const float* __restrict__ lnw, const float* __restrict__ lnb,
    unsigned short* __restrict__ t1b16) {
  __shared__ float lp[8][TOPK];
  __shared__ int li[8][TOPK];
  const int mt = blockIdx.x, b = blockIdx.y;
  const int tid = threadIdx.x;
  const int mloc = tid >> 5, kg = tid & 31, h8 = kg * 8;
  const int m = mt * 8 + mloc;
  lp[mloc][kg] = probs[(size_t)m * TOPK + kg];
  li[mloc][kg] = pidx[(size_t)m * TOPK + kg];
  __syncthreads();

  const unsigned short* sb = s16 + (size_t)b * NN * HH + h8;

  float acc[8] = {0.f, 0.f, 0.f, 0.f, 0.f, 0.f, 0.f, 0.f};
#pragma unroll
  for (int k = 0; k < TOPK; ++k) {
    const bf16x8 v = *reinterpret_cast<const bf16x8*>(sb + (size_t)li[mloc][k] * HH);
    const float p = lp[mloc][k];
#pragma unroll
    for (int e = 0; e < 8; ++e)
      acc[e] = fmaf(p, bf2f((unsigned short)v[e]), acc[e]);
  }

  const size_t obase = ((size_t)b * NN + m) * HH + h8;
  const float4 t0 = *reinterpret_cast<const float4*>(tgt + obase);
  const float4 t1 = *reinterpret_cast<const float4*>(tgt + obase + 4);
  acc[0] += t0.x; acc[1] += t0.y; acc[2] += t0.z; acc[3] += t0.w;
  acc[4] += t1.x; acc[5] += t1.y; acc[6] += t1.z; acc[7] += t1.w;

  float s = 0.f, s2 = 0.f;
#pragma unroll
  for (int e = 0; e < 8; ++e) { s += acc[e]; s2 = fmaf(acc[e], acc[e], s2); }
#pragma unroll
  for (int off = 16; off; off >>= 1) {
    s += __shfl_xor(s, off, 32);
    s2 += __shfl_xor(s2, off, 32);
  }
  const float mu = s * (1.f / HH);
  const float var = s2 * (1.f / HH) - mu * mu;
  const float rs = rsqrtf(var + LN_EPS);

  const float4 w0 = *reinterpret_cast<const float4*>(lnw + h8);
  const float4 w1 = *reinterpret_cast<const float4*>(lnw + h8 + 4);
  const float4 c0 = *reinterpret_cast<const float4*>(lnb + h8);
  const float4 c1 = *reinterpret_cast<const float4*>(lnb + h8 + 4);
  const float wv[8] = {w0.x, w0.y, w0.z, w0.w, w1.x, w1.y, w1.z, w1.w};
  const float cv[8] = {c0.x, c0.y, c0.z, c0.w, c1.x, c1.y, c1.z, c1.w};
  union { unsigned short us[8]; uint4 q; } ot;
#pragma unroll
  for (int e = 0; e < 8; ++e)
    ot.us[e] = f2bf((acc[e] - mu) * rs * wv[e] + cv[e]);
  *reinterpret_cast<uint4*>(t1b16 + obase) = ot.q;
}

// ---------------------------------------------------------------------------
// K5: out = LN2(t1b16 + ff2b16) -> d_out (fp32). 8 rows/block, 32 lanes/row.
// ---------------------------------------------------------------------------
__global__ __launch_bounds__(256) void k_res_ln2(
    const unsigned short* __restrict__ t1b16,
    const unsigned short* __restrict__ ffb16,
    const float* __restrict__ lnw, const float* __restrict__ lnb,
    float* __restrict__ out) {
  const int tid = threadIdx.x;
  const int rloc = tid >> 5, kg = tid & 31, h8 = kg * 8;
  const size_t row = (size_t)blockIdx.x * 8 + rloc;
  const size_t obase = row * HH + h8;

  const bf16x8 t = *reinterpret_cast<const bf16x8*>(t1b16 + obase);
  const bf16x8 f = *reinterpret_cast<const bf16x8*>(ffb16 + obase);
  float x[8];
#pragma unroll
  for (int e = 0; e < 8; ++e)
    x[e] = bf2f((unsigned short)t[e]) + bf2f((unsigned short)f[e]);

  float s = 0.f, s2 = 0.f;
#pragma unroll
  for (int e = 0; e < 8; ++e) { s += x[e]; s2 = fmaf(x[e], x[e], s2); }
#pragma unroll
  for (int off = 16; off; off >>= 1) {
    s += __shfl_xor(s, off, 32);
    s2 += __shfl_xor(s2, off, 32);
  }
  const float mu = s * (1.f / HH);
  const float var = s2 * (1.f / HH) - mu * mu;
  const float rs = rsqrtf(var + LN_EPS);

  const float4 w0 = *reinterpret_cast<const float4*>(lnw + h8);
  const float4 w1 = *reinterpret_cast<const float4*>(lnw + h8 + 4);
  const float4 c0 = *reinterpret_cast<const float4*>(lnb + h8);
  const float4 c1 = *reinterpret_cast<const float4*>(lnb + h8 + 4);
  float4 o0, o1;
  o0.x = (x[0] - mu) * rs * w0.x + c0.x;
  o0.y = (x[1] - mu) * rs * w0.y + c0.y;
  o0.z = (x[2] - mu) * rs * w0.z + c0.z;
  o0.w = (x[3] - mu) * rs * w0.w + c0.w;
  o1.x = (x[4] - mu) * rs * w1.x + c1.x;
  o1.y = (x[5] - mu) * rs * w1.y + c1.y;
  o1.z = (x[6] - mu) * rs * w1.z + c1.z;
  o1.w = (x[7] - mu) * rs * w1.w + c1.w;
  *reinterpret_cast<float4*>(out + obase) = o0;
  *reinterpret_cast<float4*>(out + obase + 4) = o1;
}

// ---------------------------------------------------------------------------
extern "C" void kernel_launch(void* const* d_in, const int* in_sizes, int n_in,
                              void* d_out, int out_size, void* d_ws, size_t ws_size,
                              hipStream_t stream) {
  const float* src  = (const float*)d_in[0];
  const float* tgt  = (const float*)d_in[1];
  const float* n1   = (const float*)d_in[2];
  const float* n2   = (const float*)d_in[3];
  const float* w1   = (const float*)d_in[4];
  const float* b1   = (const float*)d_in[5];
  const float* w2   = (const float*)d_in[6];
  const float* b2   = (const float*)d_in[7];
  const float* ln1w = (const float*)d_in[8];
  const float* ln1b = (const float*)d_in[9];
  const float* ln2w = (const float*)d_in[10];
  const float* ln2b = (const float*)d_in[11];
  float* out = (float*)d_out;

  // ws: probs(512K) | pidx(512K) | 64MiB region | apack 2M | bpack 2M
  //     | wpacks 256K @68M | cand 1M @69M
  // region lifetime interval map (byte offsets; audited):
  //   adjb   [0,32M)   adjgemm -> topk64 (bf16; dead before srcpack)
  //   s16    [0,16M)   srcpack -> gather (dead before ffgemm2)
  //   ff2b16 [16,32M)  ffgemm2 -> res_ln2 (overlays dead adjb upper half)
  //   ff1b16 [32,48M)  ffgemm1 -> ffgemm2
  //   t1b16  [48,64M)  gather -> ffgemm1 + res_ln2
  //   cand @69M: topk64 -> refine (outside the 64M region; no conflicts)
  float* wsf   = (float*)d_ws;
  float* probs = wsf;
  int*   pidx  = (int*)(wsf + (size_t)NN * TOPK);
  char*  cbase = (char*)(wsf + 2 * (size_t)NN * TOPK);
  unsigned short* adjb   = (unsigned short*)cbase;
  unsigned short* s16    = (unsigned short*)cbase;
  unsigned short* ff2b16 = (unsigned short*)(cbase + ((size_t)16 << 20));
  unsigned short* ff1b16 = (unsigned short*)(cbase + ((size_t)32 << 20));
  unsigned short* t1b16  = (unsigned short*)(cbase + ((size_t)48 << 20));
  unsigned short* apack  = (unsigned short*)(cbase + ((size_t)64 << 20));
  unsigned short* bpack  = (unsigned short*)(cbase + ((size_t)66 << 20));
  unsigned short* w1pack = (unsigned short*)(cbase + ((size_t)68 << 20));
  unsigned short* w2pack = w1pack + 65536;
  int* cand = (int*)(cbase + ((size_t)69 << 20));

  dim3 gp(512, 2);
  k_pack<<<gp, 256, 0, stream>>>(n1, n2, apack, bpack);
  k_adjgemm_pk<<<(NN / 128) * (NN / 128), 256, 0, stream>>>(apack, bpack, adjb);
  k_topk64<<<NN / 4, 256, 0, stream>>>(adjb, cand);
  k_refine<<<NN, 256, 0, stream>>>(n1, n2, cand, probs, pidx);

  // srcpack (4096 blocks) + packw (64 blocks) fused
  k_srcpack<<<4096 + 64, 256, 0, stream>>>(src, s16, w1, w2, w1pack, w2pack);

  dim3 gg(NN / 8, BATCH);  // single-batch blocks, x-major (L2 slab residency)
  k_gather_ln1<<<gg, 256, 0, stream>>>(s16, tgt, probs, pidx, ln1w, ln1b, t1b16);

  const int gemm_grid = (BATCH * NN / 128) * (HH / 128);  // 512
  k_ffgemm1_pk<<<gemm_grid, 256, 0, stream>>>(t1b16, w1pack, b1, ff1b16);
  k_ffgemm2_pk<<<gemm_grid, 256, 0, stream>>>(ff1b16, w2pack, b2, ff2b16);

  k_res_ln2<<<BATCH * NN / 8, 256, 0, stream>>>(t1b16, ff2b16, ln2w, ln2b, out);
}

// Round 21
// 147.068 us; speedup vs baseline: 2.9185x; 1.0613x over previous
//
#include <hip/hip_runtime.h>
#include <math.h>

#define NN 4096
#define HH 256
#define BATCH 8
#define TOPK 32
#define NSEL 64
#define LN_EPS 1e-5f

typedef float f32x4 __attribute__((ext_vector_type(4)));
typedef short bf16x8 __attribute__((ext_vector_type(8)));

__device__ __forceinline__ unsigned short f2bf(float x) {
  unsigned u = __float_as_uint(x);
  u += 0x7FFF + ((u >> 16) & 1);  // RNE
  return (unsigned short)(u >> 16);
}
__device__ __forceinline__ float bf2f(unsigned short h) {
  return __uint_as_float(((unsigned)h) << 16);
}

// async global->LDS, 16B per lane; LDS dest is wave-uniform base + lane*16
__device__ __forceinline__ void gload16(const void* g, void* l) {
  __builtin_amdgcn_global_load_lds(
      (const __attribute__((address_space(1))) void*)g,
      (__attribute__((address_space(3))) void*)l, 16, 0, 0);
}

// one BK=32 K-step: 4x4 fragment MFMAs from [g:4][row:128][8] LDS tiles
__device__ __forceinline__ void mfma_tile(const unsigned short* Al,
                                          const unsigned short* Bl,
                                          int wr, int wc, int lane,
                                          f32x4 acc[4][4]) {
  const int g = lane >> 4, r = lane & 15;
  bf16x8 a[4], b[4];
#pragma unroll
  for (int i = 0; i < 4; ++i)
    a[i] = *reinterpret_cast<const bf16x8*>(Al + ((size_t)(g * 128 + wr * 64 + i * 16 + r)) * 8);
#pragma unroll
  for (int j = 0; j < 4; ++j)
    b[j] = *reinterpret_cast<const bf16x8*>(Bl + ((size_t)(g * 128 + wc * 64 + j * 16 + r)) * 8);
#pragma unroll
  for (int i = 0; i < 4; ++i)
#pragma unroll
    for (int j = 0; j < 4; ++j)
      acc[i][j] = __builtin_amdgcn_mfma_f32_16x16x32_bf16(a[i], b[j], acc[i][j], 0, 0, 0);
}

// ---------------------------------------------------------------------------
// K0: bf16 (hi-only) pack of n1/n2 into GEMM LDS slot order. 8 K-steps.
// ---------------------------------------------------------------------------
__global__ __launch_bounds__(256) void k_pack(
    const float* __restrict__ n1, const float* __restrict__ n2,
    unsigned short* __restrict__ apack, unsigned short* __restrict__ bpack) {
  const int u = blockIdx.x * 256 + threadIdx.x;  // 0..131071
  const float* srcm = blockIdx.y ? n2 : n1;
  unsigned short* dstm = blockIdx.y ? bpack : apack;
  const int row = u >> 5, kg = u & 31;
  const int st = kg >> 2, g = kg & 3;
  const int bm = row >> 7, slot = g * 128 + (row & 127);

  const float4 v0 = *reinterpret_cast<const float4*>(srcm + (size_t)row * HH + kg * 8);
  const float4 v1 = *reinterpret_cast<const float4*>(srcm + (size_t)row * HH + kg * 8 + 4);
  const float xs[8] = {v0.x, v0.y, v0.z, v0.w, v1.x, v1.y, v1.z, v1.w};
  union { unsigned short s[8]; uint4 q; } hi;
#pragma unroll
  for (int e = 0; e < 8; ++e) hi.s[e] = f2bf(xs[e]);
  *reinterpret_cast<uint4*>(dstm + ((size_t)(bm * 8 + st) * 512 + slot) * 8) = hi.q;
}

// ---------------------------------------------------------------------------
// K0b: src fp32 -> bf16 (blocks 0..4095) + w1/w2 slot-order packs (blocks
// 4096..4159). Runs AFTER k_topk64.
// ---------------------------------------------------------------------------
__global__ __launch_bounds__(256) void k_srcpack(
    const float* __restrict__ src, unsigned short* __restrict__ s16,
    const float* __restrict__ w1, const float* __restrict__ w2,
    unsigned short* __restrict__ w1pack, unsigned short* __restrict__ w2pack) {
  if (blockIdx.x < 4096) {
    const size_t i = ((size_t)blockIdx.x * 256 + threadIdx.x) * 8;
    const float4 v0 = *reinterpret_cast<const float4*>(src + i);
    const float4 v1 = *reinterpret_cast<const float4*>(src + i + 4);
    const float xs[8] = {v0.x, v0.y, v0.z, v0.w, v1.x, v1.y, v1.z, v1.w};
    union { unsigned short s[8]; uint4 q; } p;
#pragma unroll
    for (int e = 0; e < 8; ++e) p.s[e] = f2bf(xs[e]);
    *reinterpret_cast<uint4*>(s16 + i) = p.q;
  } else {
    const int idx = (blockIdx.x - 4096) * 256 + threadIdx.x;  // 0..16383
    const int mat = idx >> 13, u = idx & 8191;
    const float* srcm = mat ? w2 : w1;
    unsigned short* dstm = mat ? w2pack : w1pack;
    const int row = u >> 5, kg = u & 31;
    const int st = kg >> 2, g = kg & 3;
    const int bn = row >> 7, slot = g * 128 + (row & 127);
    const float4 v0 = *reinterpret_cast<const float4*>(srcm + (size_t)row * HH + kg * 8);
    const float4 v1 = *reinterpret_cast<const float4*>(srcm + (size_t)row * HH + kg * 8 + 4);
    const float xs[8] = {v0.x, v0.y, v0.z, v0.w, v1.x, v1.y, v1.z, v1.w};
    union { unsigned short s[8]; uint4 q; } p;
#pragma unroll
    for (int e = 0; e < 8; ++e) p.s[e] = f2bf(xs[e]);
    *reinterpret_cast<uint4*>(dstm + ((size_t)(bn * 8 + st) * 512 + slot) * 8) = p.q;
  }
}

// ---------------------------------------------------------------------------
// K1a: adjb ~= bf16(n1 @ n2^T), ONE bf16 phase (selection-only; exact values
// recomputed by k_refine). 8 K-steps, XCD-swizzled. grid 1024.
// ---------------------------------------------------------------------------
__global__ __launch_bounds__(256) void k_adjgemm_pk(
    const unsigned short* __restrict__ apack,
    const unsigned short* __restrict__ bpack,
    unsigned short* __restrict__ adjb) {
  __shared__ __align__(16) unsigned short Al[512 * 8];
  __shared__ __align__(16) unsigned short Bl[512 * 8];
  const int tid = threadIdx.x;
  const int lane = tid & 63, wid = tid >> 6;
  const int wr = wid >> 1, wc = wid & 1;
  const int wgid = (blockIdx.x & 7) * 128 + (blockIdx.x >> 3);  // XCD swizzle
  const int bm = wgid >> 5, bn = wgid & 31;
  const int m0 = bm * 128, n0 = bn * 128;

  f32x4 acc[4][4];
#pragma unroll
  for (int i = 0; i < 4; ++i)
#pragma unroll
    for (int j = 0; j < 4; ++j) acc[i][j] = (f32x4){0.f, 0.f, 0.f, 0.f};

  unsigned short* lA0 = Al + (size_t)(wid * 64) * 8;
  unsigned short* lA1 = Al + (size_t)(256 + wid * 64) * 8;
  unsigned short* lB0 = Bl + (size_t)(wid * 64) * 8;
  unsigned short* lB1 = Bl + (size_t)(256 + wid * 64) * 8;

  for (int t = 0; t < 8; ++t) {
    const unsigned short* ga = apack + (size_t)(bm * 8 + t) * 4096;
    const unsigned short* gb = bpack + (size_t)(bn * 8 + t) * 4096;
    __syncthreads();
    gload16(ga + (size_t)tid * 8, lA0);
    gload16(ga + (size_t)(256 + tid) * 8, lA1);
    gload16(gb + (size_t)tid * 8, lB0);
    gload16(gb + (size_t)(256 + tid) * 8, lB1);
    __syncthreads();
    mfma_tile(Al, Bl, wr, wc, lane, acc);
  }

  const int crow = m0 + wr * 64 + (lane >> 4) * 4;
  const int ccol = n0 + wc * 64 + (lane & 15);
#pragma unroll
  for (int i = 0; i < 4; ++i)
#pragma unroll
    for (int j = 0; j < 4; ++j) {
      unsigned short* cp = adjb + (size_t)(crow + i * 16) * NN + ccol + j * 16;
#pragma unroll
      for (int q = 0; q < 4; ++q) cp[(size_t)q * NN] = f2bf(acc[i][j][q]);
    }
}

// ---------------------------------------------------------------------------
// K1b: per-row approx top-64 candidate indices via ballot-bisection, from
// the bf16 adj. Keys unique via idx field.
// ---------------------------------------------------------------------------
__global__ __launch_bounds__(256) void k_topk64(
    const unsigned short* __restrict__ adjb, int* __restrict__ cand) {
  const int tid = threadIdx.x;
  const int wid = tid >> 6, lane = tid & 63;
  const int r = blockIdx.x * 4 + wid;
  const bf16x8* rp8 = reinterpret_cast<const bf16x8*>(adjb + (size_t)r * NN);

#define KEY(v, ix) ((((unsigned long long)__float_as_uint(v)) << 32) | \
                    (unsigned)(NN - 1 - (ix)))

  unsigned long long k1 = 0, k2 = 0, k3 = 0, k4 = 0;
  unsigned long long k5 = 0, k6 = 0, k7 = 0, k8 = 0;

#define INS4(kk)                                              \
  do { const unsigned long long _k = (kk);                    \
    if (_k > k4) {                                            \
      if (_k > k1)      { k4 = k3; k3 = k2; k2 = k1; k1 = _k; } \
      else if (_k > k2) { k4 = k3; k3 = k2; k2 = _k; }        \
      else if (_k > k3) { k4 = k3; k3 = _k; }                 \
      else              { k4 = _k; } } } while (0)
#define INS8(kk)                                              \
  do { const unsigned long long _k = (kk);                    \
    if (_k > k8) {                                            \
      if (_k > k5)      { k8 = k7; k7 = k6; k6 = k5; k5 = _k; } \
      else if (_k > k6) { k8 = k7; k7 = k6; k6 = _k; }        \
      else if (_k > k7) { k8 = k7; k7 = _k; }                 \
      else              { k8 = _k; } } } while (0)

#pragma unroll
  for (int j = 0; j < 8; ++j) {
    const bf16x8 v = rp8[j * 64 + lane];
    const int ib = (j * 64 + lane) * 8;
#pragma unroll
    for (int e = 0; e < 8; ++e)
      INS4(KEY(bf2f((unsigned short)v[e]), ib + e));
  }

  auto bisect = [&]() -> unsigned long long {
    unsigned long long T = 0;
#pragma unroll 1
    for (int b = 63; b >= 32; --b) {
      const unsigned long long Tp = T | (1ULL << b);
      const int cnt = __popcll(__ballot(k1 >= Tp)) + __popcll(__ballot(k2 >= Tp)) +
                      __popcll(__ballot(k3 >= Tp)) + __popcll(__ballot(k4 >= Tp)) +
                      __popcll(__ballot(k5 >= Tp)) + __popcll(__ballot(k6 >= Tp)) +
                      __popcll(__ballot(k7 >= Tp)) + __popcll(__ballot(k8 >= Tp));
      if (cnt >= NSEL) T = Tp;
    }
#pragma unroll 1
    for (int b = 11; b >= 0; --b) {
      const unsigned long long Tp = T | (1ULL << b);
      const int cnt = __popcll(__ballot(k1 >= Tp)) + __popcll(__ballot(k2 >= Tp)) +
                      __popcll(__ballot(k3 >= Tp)) + __popcll(__ballot(k4 >= Tp)) +
                      __popcll(__ballot(k5 >= Tp)) + __popcll(__ballot(k6 >= Tp)) +
                      __popcll(__ballot(k7 >= Tp)) + __popcll(__ballot(k8 >= Tp));
      if (cnt >= NSEL) T = Tp;
    }
    return T;
  };

  unsigned long long T = bisect();

  if (__any(k4 >= T)) {
    if (k4 >= T) {  // suspect lanes build their next-4 (keys < k4)
      const unsigned long long kmin = k4;
#pragma unroll 1
      for (int j = 0; j < 8; ++j) {
        const bf16x8 v = rp8[j * 64 + lane];
        const int ib = (j * 64 + lane) * 8;
#pragma unroll
        for (int e = 0; e < 8; ++e) {
          const unsigned long long kk = KEY(bf2f((unsigned short)v[e]), ib + e);
          if (kk < kmin) INS8(kk);
        }
      }
    }
    T = bisect();
    if (__any(k8 >= T)) {
      // exact serial fallback (rare): 64 ordered extractions
      unsigned long long W = ~0ULL;
      int outi = 0;
#pragma unroll 1
      for (int it = 0; it < NSEL; ++it) {
        unsigned long long best = 0;
        for (int j = 0; j < 8; ++j) {
          const bf16x8 v = rp8[j * 64 + lane];
          const int ib = (j * 64 + lane) * 8;
#pragma unroll
          for (int e = 0; e < 8; ++e) {
            const unsigned long long kk = KEY(bf2f((unsigned short)v[e]), ib + e);
            if (kk < W && kk > best) best = kk;
          }
        }
#pragma unroll
        for (int off = 32; off; off >>= 1) {
          const unsigned long long o = __shfl_xor(best, off);
          if (o > best) best = o;
        }
        if (lane == it) outi = NN - 1 - (int)(best & 0xFFFFFFFFu);
        W = best;
      }
      cand[(size_t)r * NSEL + lane] = outi;
      return;
    }
  }

  // emission: keys >= T (exactly 64), arbitrary order
  const unsigned long long m1 = __ballot(k1 >= T), m2 = __ballot(k2 >= T);
  const unsigned long long m3 = __ballot(k3 >= T), m4 = __ballot(k4 >= T);
  const unsigned long long m5 = __ballot(k5 >= T), m6 = __ballot(k6 >= T);
  const unsigned long long m7 = __ballot(k7 >= T), m8 = __ballot(k8 >= T);

  auto mb = [](unsigned long long m) -> int {
    return (int)__builtin_amdgcn_mbcnt_hi(
        (unsigned)(m >> 32), __builtin_amdgcn_mbcnt_lo((unsigned)m, 0));
  };
  const int c1 = __popcll(m1), c2 = __popcll(m2), c3 = __popcll(m3);
  const int c4 = __popcll(m4), c5 = __popcll(m5), c6 = __popcll(m6);
  const int c7 = __popcll(m7);
  const int b2 = c1, b3 = b2 + c2, b4 = b3 + c3, b5 = b4 + c4;
  const int b6 = b5 + c5, b7 = b6 + c6, b8 = b7 + c7;

  int* cp = cand + (size_t)r * NSEL;
  if (k1 >= T) cp[     mb(m1)] = NN - 1 - (int)(k1 & 0xFFFFFFFFu);
  if (k2 >= T) cp[b2 + mb(m2)] = NN - 1 - (int)(k2 & 0xFFFFFFFFu);
  if (k3 >= T) cp[b3 + mb(m3)] = NN - 1 - (int)(k3 & 0xFFFFFFFFu);
  if (k4 >= T) cp[b4 + mb(m4)] = NN - 1 - (int)(k4 & 0xFFFFFFFFu);
  if (k5 >= T) cp[b5 + mb(m5)] = NN - 1 - (int)(k5 & 0xFFFFFFFFu);
  if (k6 >= T) cp[b6 + mb(m6)] = NN - 1 - (int)(k6 & 0xFFFFFFFFu);
  if (k7 >= T) cp[b7 + mb(m7)] = NN - 1 - (int)(k7 & 0xFFFFFFFFu);
  if (k8 >= T) cp[b8 + mb(m8)] = NN - 1 - (int)(k8 & 0xFFFFFFFFu);
#undef INS4
#undef INS8
#undef KEY
}

// ---------------------------------------------------------------------------
// K1c: exact refine, coalesced (interleaved segments). One block per row;
// 4 lanes/candidate, lane s reads float4 idx j*4+s. Wave 0: exact
// top-32-of-64 bisect + softmax + mbcnt emission.
// ---------------------------------------------------------------------------
__global__ __launch_bounds__(256) void k_refine(
    const float* __restrict__ n1, const float* __restrict__ n2,
    const int* __restrict__ cand,
    float* __restrict__ probs, int* __restrict__ pidx) {
  __shared__ float a_sh[HH];
  __shared__ float cv[NSEL];
  __shared__ int ci[NSEL];
  const int r = blockIdx.x;
  const int tid = threadIdx.x;

  a_sh[tid] = n1[(size_t)r * HH + tid];
  const int c = cand[(size_t)r * NSEL + (tid >> 2)];
  __syncthreads();

  const int s = tid & 3;  // interleave: float4 index j*4+s
  const float4* br = reinterpret_cast<const float4*>(n2 + (size_t)c * HH);
  const float4* ar = reinterpret_cast<const float4*>(a_sh);
  float a0 = 0.f, a1 = 0.f, a2 = 0.f, a3 = 0.f;
#pragma unroll
  for (int j = 0; j < 16; j += 4) {
    const float4 bx = br[(j + 0) * 4 + s];
    const float4 by = br[(j + 1) * 4 + s];
    const float4 bz = br[(j + 2) * 4 + s];
    const float4 bw = br[(j + 3) * 4 + s];
    const float4 ax = ar[(j + 0) * 4 + s];
    const float4 ay = ar[(j + 1) * 4 + s];
    const float4 az = ar[(j + 2) * 4 + s];
    const float4 aw = ar[(j + 3) * 4 + s];
    a0 = fmaf(ax.x, bx.x, fmaf(ax.y, bx.y, fmaf(ax.z, bx.z, fmaf(ax.w, bx.w, a0))));
    a1 = fmaf(ay.x, by.x, fmaf(ay.y, by.y, fmaf(ay.z, by.z, fmaf(ay.w, by.w, a1))));
    a2 = fmaf(az.x, bz.x, fmaf(az.y, bz.y, fmaf(az.z, bz.z, fmaf(az.w, bz.w, a2))));
    a3 = fmaf(aw.x, bw.x, fmaf(aw.y, bw.y, fmaf(aw.z, bw.z, fmaf(aw.w, bw.w, a3))));
  }
  float acc = (a0 + a1) + (a2 + a3);
  acc += __shfl_xor(acc, 1);
  acc += __shfl_xor(acc, 2);
  if ((tid & 3) == 0) { cv[tid >> 2] = acc; ci[tid >> 2] = c; }
  __syncthreads();

  if (tid < NSEL) {  // wave 0: lane = candidate
    const float v = cv[tid];
    const int cc = ci[tid];
    const unsigned long long key =
        (((unsigned long long)__float_as_uint(v)) << 32) | (unsigned)(NN - 1 - cc);

    unsigned long long T = 0;
#pragma unroll 1
    for (int b = 63; b >= 32; --b) {
      const unsigned long long Tp = T | (1ULL << b);
      if (__popcll(__ballot(key >= Tp)) >= TOPK) T = Tp;
    }
#pragma unroll 1
    for (int b = 11; b >= 0; --b) {
      const unsigned long long Tp = T | (1ULL << b);
      if (__popcll(__ballot(key >= Tp)) >= TOPK) T = Tp;
    }

    const bool win = (key >= T);  // exactly 32 lanes
    float mx = v;
#pragma unroll
    for (int off = 32; off; off >>= 1) mx = fmaxf(mx, __shfl_xor(mx, off));
    const float e = win ? expf(v - mx) : 0.f;
    float sum = e;
#pragma unroll
    for (int off = 32; off; off >>= 1) sum += __shfl_xor(sum, off);

    const unsigned long long wm = __ballot(win);
    if (win) {
      const int slot = (int)__builtin_amdgcn_mbcnt_hi(
          (unsigned)(wm >> 32), __builtin_amdgcn_mbcnt_lo((unsigned)wm, 0));
      probs[(size_t)r * TOPK + slot] = e / sum;
      pidx [(size_t)r * TOPK + slot] = cc;
    }
  }
}

// ---------------------------------------------------------------------------
// K3: ff1 = relu(tgt1 @ w1^T + b1). A reg-staged from row-major bf16 t1b16,
// B via gload16 from w1pack. bf16 row-major out. grid 512.
// ---------------------------------------------------------------------------
__global__ __launch_bounds__(256) void k_ffgemm1_pk(
    const unsigned short* __restrict__ Ab16,
    const unsigned short* __restrict__ wpk,
    const float* __restrict__ bias,
    unsigned short* __restrict__ Cb) {
  __shared__ __align__(16) unsigned short Al[512 * 8];
  __shared__ __align__(16) unsigned short Bl[512 * 8];
  const int tid = threadIdx.x;
  const int lane = tid & 63, wid = tid >> 6;
  const int wr = wid >> 1, wc = wid & 1;
  const int bm = blockIdx.x >> 1, bn = blockIdx.x & 1;
  const int m0 = bm * 128, n0 = bn * 128;

  f32x4 acc[4][4];
#pragma unroll
  for (int i = 0; i < 4; ++i)
#pragma unroll
    for (int j = 0; j < 4; ++j) acc[i][j] = (f32x4){0.f, 0.f, 0.f, 0.f};

  unsigned short* lB0 = Bl + (size_t)(wid * 64) * 8;
  unsigned short* lB1 = Bl + (size_t)(256 + wid * 64) * 8;
  const int row0 = tid & 127, g0 = tid >> 7, g1 = g0 + 2;

  for (int t = 0; t < 8; ++t) {
    const unsigned short* gw = wpk + (size_t)(bn * 8 + t) * 4096;
    __syncthreads();
    const uint4 a0 = *reinterpret_cast<const uint4*>(
        Ab16 + (size_t)(m0 + row0) * HH + t * 32 + g0 * 8);
    const uint4 a1 = *reinterpret_cast<const uint4*>(
        Ab16 + (size_t)(m0 + row0) * HH + t * 32 + g1 * 8);
    *reinterpret_cast<uint4*>(Al + (size_t)tid * 8) = a0;
    *reinterpret_cast<uint4*>(Al + (size_t)(256 + tid) * 8) = a1;
    gload16(gw + (size_t)tid * 8, lB0);
    gload16(gw + (size_t)(256 + tid) * 8, lB1);
    __syncthreads();
    mfma_tile(Al, Bl, wr, wc, lane, acc);
  }

  const int crow = m0 + wr * 64 + (lane >> 4) * 4;
  const int ccol = n0 + wc * 64 + (lane & 15);
#pragma unroll
  for (int i = 0; i < 4; ++i)
#pragma unroll
    for (int j = 0; j < 4; ++j) {
      const float bv = bias[ccol + j * 16];
      unsigned short* cp = Cb + (size_t)(crow + i * 16) * HH + ccol + j * 16;
#pragma unroll
      for (int q = 0; q < 4; ++q)
        cp[(size_t)q * HH] = f2bf(fmaxf(acc[i][j][q] + bv, 0.f));
    }
}

// ---------------------------------------------------------------------------
// K4+K5 FUSED: per 64-row stripe, ff2 = ff1 @ w2^T + b2 stays in registers;
// epilogue adds t1 residual, does LN2 (width-16 butterfly + 2KB LDS cross-
// wave partials), writes fp32 out. BM=64 x BN=256 (full rows in-block),
// 4 waves = 4 col-quadrants, grid 512. ff2 never touches memory (and stays
// fp32 — better than R20's bf16 round-trip). Eliminates k_res_ln2 + 33.5MB.
// ---------------------------------------------------------------------------
__global__ __launch_bounds__(256) void k_ffgemm2_ln2(
    const unsigned short* __restrict__ Ab16,   // ff1b16 row-major
    const unsigned short* __restrict__ wpk,    // w2pack slot order
    const float* __restrict__ bias,            // b2
    const unsigned short* __restrict__ t1b16,  // residual
    const float* __restrict__ lnw, const float* __restrict__ lnb,
    float* __restrict__ out) {
  __shared__ __align__(16) unsigned short Al[256 * 8];   // [g:4][row:64][8]
  __shared__ __align__(16) unsigned short Bl[1024 * 8];  // [bn:2][g:4][128][8]
  __shared__ float psum[64][4], psq[64][4];
  const int tid = threadIdx.x;
  const int lane = tid & 63, wid = tid >> 6;  // wave = col quadrant
  const int m0 = blockIdx.x * 64;
  const int g = lane >> 4, r = lane & 15;

  f32x4 acc[4][4];
#pragma unroll
  for (int i = 0; i < 4; ++i)
#pragma unroll
    for (int j = 0; j < 4; ++j) acc[i][j] = (f32x4){0.f, 0.f, 0.f, 0.f};

  for (int t = 0; t < 8; ++t) {
    __syncthreads();
    // A: 64 rows x 32 K, reg-staged; slot = (tid>>6)*64 + (tid&63) = tid
    const uint4 av = *reinterpret_cast<const uint4*>(
        Ab16 + (size_t)(m0 + (tid & 63)) * HH + t * 32 + (tid >> 6) * 8);
    *reinterpret_cast<uint4*>(Al + (size_t)tid * 8) = av;
    // B: all 256 w2 rows; dest slot = bn*512 + g*128 + (n&127); 4 wave-loads
#pragma unroll
    for (int c2 = 0; c2 < 4; ++c2) {
      const int sbase = c2 * 256 + wid * 64;  // wave-uniform; 64-slot range
      const int bn = sbase >> 9;              // stays within one half
      const int rem = sbase & 511;
      gload16(wpk + ((size_t)((bn * 8 + t) * 512 + rem + lane)) * 8,
              Bl + (size_t)sbase * 8);
    }
    __syncthreads();
    bf16x8 a[4], b[4];
#pragma unroll
    for (int i = 0; i < 4; ++i)
      a[i] = *reinterpret_cast<const bf16x8*>(Al + (size_t)(g * 64 + i * 16 + r) * 8);
#pragma unroll
    for (int j = 0; j < 4; ++j) {
      const int n = wid * 64 + j * 16 + r;
      const int slot = (n >> 7) * 512 + g * 128 + (n & 127);
      b[j] = *reinterpret_cast<const bf16x8*>(Bl + (size_t)slot * 8);
    }
#pragma unroll
    for (int i = 0; i < 4; ++i)
#pragma unroll
      for (int j = 0; j < 4; ++j)
        acc[i][j] = __builtin_amdgcn_mfma_f32_16x16x32_bf16(a[i], b[j], acc[i][j], 0, 0, 0);
  }

  // ---- epilogue: bias + residual, LN2, fp32 store ----
  float bv[4], lw[4], lbv[4];
#pragma unroll
  for (int j = 0; j < 4; ++j) {
    const int c = wid * 64 + j * 16 + r;
    bv[j] = bias[c]; lw[j] = lnw[c]; lbv[j] = lnb[c];
  }
#pragma unroll
  for (int i = 0; i < 4; ++i)
#pragma unroll
    for (int j = 0; j < 4; ++j) {
      const int c = wid * 64 + j * 16 + r;
#pragma unroll
      for (int q = 0; q < 4; ++q) {
        const int rl = i * 16 + g * 4 + q;
        acc[i][j][q] += bv[j] + bf2f(t1b16[(size_t)(m0 + rl) * HH + c]);
      }
    }
  // per-row partials: sum over this thread's 4 cols, butterfly over 16 lanes
#pragma unroll
  for (int i = 0; i < 4; ++i)
#pragma unroll
    for (int q = 0; q < 4; ++q) {
      float s = acc[i][0][q] + acc[i][1][q] + acc[i][2][q] + acc[i][3][q];
      float s2 = fmaf(acc[i][0][q], acc[i][0][q],
                 fmaf(acc[i][1][q], acc[i][1][q],
                 fmaf(acc[i][2][q], acc[i][2][q],
                      acc[i][3][q] * acc[i][3][q])));
#pragma unroll
      for (int off = 1; off < 16; off <<= 1) {
        s += __shfl_xor(s, off, 16);
        s2 += __shfl_xor(s2, off, 16);
      }
      if (r == 0) {
        const int rl = i * 16 + g * 4 + q;
        psum[rl][wid] = s; psq[rl][wid] = s2;
      }
    }
  __syncthreads();
#pragma unroll
  for (int i = 0; i < 4; ++i)
#pragma unroll
    for (int q = 0; q < 4; ++q) {
      const int rl = i * 16 + g * 4 + q;
      const float s = psum[rl][0] + psum[rl][1] + psum[rl][2] + psum[rl][3];
      const float s2 = psq[rl][0] + psq[rl][1] + psq[rl][2] + psq[rl][3];
      const float mu = s * (1.f / HH);
      const float var = s2 * (1.f / HH) - mu * mu;
      const float rs = rsqrtf(var + LN_EPS);
#pragma unroll
      for (int j = 0; j < 4; ++j) {
        const int c = wid * 64 + j * 16 + r;
        out[(size_t)(m0 + rl) * HH + c] = (acc[i][j][q] - mu) * rs * lw[j] + lbv[j];
      }
    }
}

// ---------------------------------------------------------------------------
// K2: gc gather (bf16 src) + residual + LN1 -> t1b16 (bf16 row-major).
// Single-batch blocks, grid (512, 8) x-major. NOTE: plain launch_bounds(256)
// — R18's (256,8) cap raised occupancy 17->81% but co-resident blocks then
// spanned multiple batch slabs, blowing the 4MB per-XCD L2 working set
// (FETCH 27.7 -> 361 MB, 38.8 -> 299 us). Low occupancy here is protective.
// ---------------------------------------------------------------------------
__global__ __launch_bounds__(256) void k_gather_ln1(
    const unsigned short* __restrict__ s16, const float* __restrict__ tgt,
    const float* __restrict__ probs, const int* __restrict__ pidx,
    const float* __restrict__ lnw, const float* __restrict__ lnb,
    unsigned short* __restrict__ t1b16) {
  __shared__ float lp[8][TOPK];
  __shared__ int li[8][TOPK];
  const int mt = blockIdx.x, b = blockIdx.y;
  const int tid = threadIdx.x;
  const int mloc = tid >> 5, kg = tid & 31, h8 = kg * 8;
  const int m = mt * 8 + mloc;
  lp[mloc][kg] = probs[(size_t)m * TOPK + kg];
  li[mloc][kg] = pidx[(size_t)m * TOPK + kg];
  __syncthreads();

  const unsigned short* sb = s16 + (size_t)b * NN * HH + h8;

  float acc[8] = {0.f, 0.f, 0.f, 0.f, 0.f, 0.f, 0.f, 0.f};
#pragma unroll
  for (int k = 0; k < TOPK; ++k) {
    const bf16x8 v = *reinterpret_cast<const bf16x8*>(sb + (size_t)li[mloc][k] * HH);
    const float p = lp[mloc][k];
#pragma unroll
    for (int e = 0; e < 8; ++e)
      acc[e] = fmaf(p, bf2f((unsigned short)v[e]), acc[e]);
  }

  const size_t obase = ((size_t)b * NN + m) * HH + h8;
  const float4 t0 = *reinterpret_cast<const float4*>(tgt + obase);
  const float4 t1 = *reinterpret_cast<const float4*>(tgt + obase + 4);
  acc[0] += t0.x; acc[1] += t0.y; acc[2] += t0.z; acc[3] += t0.w;
  acc[4] += t1.x; acc[5] += t1.y; acc[6] += t1.z; acc[7] += t1.w;

  float s = 0.f, s2 = 0.f;
#pragma unroll
  for (int e = 0; e < 8; ++e) { s += acc[e]; s2 = fmaf(acc[e], acc[e], s2); }
#pragma unroll
  for (int off = 16; off; off >>= 1) {
    s += __shfl_xor(s, off, 32);
    s2 += __shfl_xor(s2, off, 32);
  }
  const float mu = s * (1.f / HH);
  const float var = s2 * (1.f / HH) - mu * mu;
  const float rs = rsqrtf(var + LN_EPS);

  const float4 w0 = *reinterpret_cast<const float4*>(lnw + h8);
  const float4 w1 = *reinterpret_cast<const float4*>(lnw + h8 + 4);
  const float4 c0 = *reinterpret_cast<const float4*>(lnb + h8);
  const float4 c1 = *reinterpret_cast<const float4*>(lnb + h8 + 4);
  const float wv[8] = {w0.x, w0.y, w0.z, w0.w, w1.x, w1.y, w1.z, w1.w};
  const float cv[8] = {c0.x, c0.y, c0.z, c0.w, c1.x, c1.y, c1.z, c1.w};
  union { unsigned short us[8]; uint4 q; } ot;
#pragma unroll
  for (int e = 0; e < 8; ++e)
    ot.us[e] = f2bf((acc[e] - mu) * rs * wv[e] + cv[e]);
  *reinterpret_cast<uint4*>(t1b16 + obase) = ot.q;
}

// ---------------------------------------------------------------------------
extern "C" void kernel_launch(void* const* d_in, const int* in_sizes, int n_in,
                              void* d_out, int out_size, void* d_ws, size_t ws_size,
                              hipStream_t stream) {
  const float* src  = (const float*)d_in[0];
  const float* tgt  = (const float*)d_in[1];
  const float* n1   = (const float*)d_in[2];
  const float* n2   = (const float*)d_in[3];
  const float* w1   = (const float*)d_in[4];
  const float* b1   = (const float*)d_in[5];
  const float* w2   = (const float*)d_in[6];
  const float* b2   = (const float*)d_in[7];
  const float* ln1w = (const float*)d_in[8];
  const float* ln1b = (const float*)d_in[9];
  const float* ln2w = (const float*)d_in[10];
  const float* ln2b = (const float*)d_in[11];
  float* out = (float*)d_out;

  // ws: probs(512K) | pidx(512K) | 64MiB region | apack 2M | bpack 2M
  //     | wpacks 256K @68M | cand 1M @69M
  // region lifetime interval map (byte offsets; audited):
  //   adjb   [0,32M)   adjgemm -> topk64 (bf16; dead before srcpack)
  //   s16    [0,16M)   srcpack -> gather
  //   ff1b16 [32,48M)  ffgemm1 -> ffgemm2_ln2
  //   t1b16  [48,64M)  gather -> ffgemm1 + ffgemm2_ln2
  //   cand @69M: topk64 -> refine (outside the 64M region; no conflicts)
  //   (ff2 eliminated: lives in ffgemm2_ln2 registers)
  float* wsf   = (float*)d_ws;
  float* probs = wsf;
  int*   pidx  = (int*)(wsf + (size_t)NN * TOPK);
  char*  cbase = (char*)(wsf + 2 * (size_t)NN * TOPK);
  unsigned short* adjb   = (unsigned short*)cbase;
  unsigned short* s16    = (unsigned short*)cbase;
  unsigned short* ff1b16 = (unsigned short*)(cbase + ((size_t)32 << 20));
  unsigned short* t1b16  = (unsigned short*)(cbase + ((size_t)48 << 20));
  unsigned short* apack  = (unsigned short*)(cbase + ((size_t)64 << 20));
  unsigned short* bpack  = (unsigned short*)(cbase + ((size_t)66 << 20));
  unsigned short* w1pack = (unsigned short*)(cbase + ((size_t)68 << 20));
  unsigned short* w2pack = w1pack + 65536;
  int* cand = (int*)(cbase + ((size_t)69 << 20));

  dim3 gp(512, 2);
  k_pack<<<gp, 256, 0, stream>>>(n1, n2, apack, bpack);
  k_adjgemm_pk<<<(NN / 128) * (NN / 128), 256, 0, stream>>>(apack, bpack, adjb);
  k_topk64<<<NN / 4, 256, 0, stream>>>(adjb, cand);
  k_refine<<<NN, 256, 0, stream>>>(n1, n2, cand, probs, pidx);

  // srcpack (4096 blocks) + packw (64 blocks) fused
  k_srcpack<<<4096 + 64, 256, 0, stream>>>(src, s16, w1, w2, w1pack, w2pack);

  dim3 gg(NN / 8, BATCH);  // single-batch blocks, x-major (L2 slab residency)
  k_gather_ln1<<<gg, 256, 0, stream>>>(s16, tgt, probs, pidx, ln1w, ln1b, t1b16);

  const int gemm_grid = (BATCH * NN / 128) * (HH / 128);  // 512
  k_ffgemm1_pk<<<gemm_grid, 256, 0, stream>>>(t1b16, w1pack, b1, ff1b16);

  // fused ff2 GEMM + residual + LN2 (BM=64 full-row tiles, grid 512)
  k_ffgemm2_ln2<<<(BATCH * NN) / 64, 256, 0, stream>>>(
      ff1b16, w2pack, b2, t1b16, ln2w, ln2b, out);
}